// Round 2
// baseline (34711.157 us; speedup 1.0000x reference)
//
#include <hip/hip_runtime.h>
#include <hip/hip_bf16.h>

#define BB 64
#define SS 1024
#define MEL 60
#define HH 180
#define G4 720   // 4*H
#define NL 4
#define NPOST 8192
#define NOUT 300
#define TT 128   // mel time tile
#define CH 128   // lstm time chunk

// ---------------- prep kernels ----------------
__global__ void prep_whhT(const float* __restrict__ whh, float* __restrict__ whhT) {
    int idx = blockIdx.x * blockDim.x + threadIdx.x;
    int total = NL * G4 * HH;
    if (idx >= total) return;
    int l = idx / (G4 * HH);
    int rem = idx % (G4 * HH);
    int g = rem / HH;
    int k = rem % HH;
    // whhT[l][k][g] = whh[l][g][k]
    whhT[((size_t)l * HH + k) * G4 + g] = whh[idx];
}

__global__ void prep_bsum(const float* __restrict__ bih, const float* __restrict__ bhh,
                          float* __restrict__ bsum) {
    int idx = blockIdx.x * blockDim.x + threadIdx.x;
    if (idx >= NL * G4) return;
    bsum[idx] = bih[idx] + bhh[idx];
}

// ---------------- mel smooth residual block ----------------
// in/out layout: (B, S, MEL), conv along S (pad 2), grouped: out ch 3i+j reads in ch 3i+j-1+c
__global__ __launch_bounds__(256) void mel_block(const float* __restrict__ in,
                                                 float* __restrict__ out,
                                                 const float* __restrict__ w,   // (3,20,3,5)
                                                 const float* __restrict__ bias) { // (3,20)
    __shared__ float xt[TT + 4][MEL];
    __shared__ float ws[900];
    __shared__ float bs[MEL];
    int bb = blockIdx.x;
    int t0 = blockIdx.y * TT;
    int tid = threadIdx.x;
    const float* inb = in + (size_t)bb * SS * MEL;
    for (int idx = tid; idx < (TT + 4) * MEL; idx += 256) {
        int tt = idx / MEL, ch = idx % MEL;
        int t = t0 + tt - 2;
        xt[tt][ch] = (t >= 0 && t < SS) ? inb[(size_t)t * MEL + ch] : 0.f;
    }
    for (int idx = tid; idx < 900; idx += 256) ws[idx] = w[idx];
    if (tid < MEL) bs[tid] = bias[(tid % 3) * 20 + tid / 3];  // out ch 3i+j gets b[j][i]
    __syncthreads();
    for (int idx = tid; idx < TT * MEL; idx += 256) {
        int tt = idx / MEL, ch = idx % MEL;
        int i = ch / 3, j = ch % 3;
        int qb = 3 * i + (j - 1);
        float acc = bs[ch];
        #pragma unroll
        for (int c = 0; c < 3; ++c) {
            int q = qb + c;
            if (q >= 0 && q < MEL) {
                const float* wp = ws + ((j * 20 + i) * 3 + c) * 5;
                #pragma unroll
                for (int k = 0; k < 5; ++k) acc += xt[tt + k][q] * wp[k];
            }
        }
        out[(size_t)bb * SS * MEL + (size_t)(t0 + tt) * MEL + ch] = acc + xt[tt + 2][ch];
    }
}

// ---------------- input GEMM (chunked): one block = one batch's 128-step chunk ----------------
// A: (B, S, K) row-major; W: (720, K); C: (B, CH, 720)
__global__ __launch_bounds__(256) void gemm_pre(const float* __restrict__ A, int K, int t0,
                                                const float* __restrict__ W,
                                                const float* __restrict__ bsum,
                                                float* __restrict__ C) {
    __shared__ float As[16][132];
    __shared__ float Wsh[16][68];
    const float* Ab = A + ((size_t)blockIdx.x * SS + t0) * K;
    float* Cb = C + (size_t)blockIdx.x * CH * G4;
    int n0 = blockIdx.y * 64;
    int tid = threadIdx.x;
    int kk = tid & 15, q = tid >> 4;
    int tx = tid & 15, ty = tid >> 4;
    float acc[8][4];
    #pragma unroll
    for (int i = 0; i < 8; ++i)
        #pragma unroll
        for (int j = 0; j < 4; ++j) acc[i][j] = 0.f;

    int ktiles = (K + 15) / 16;
    for (int kt = 0; kt < ktiles; ++kt) {
        int kidx = kt * 16 + kk;
        bool kval = kidx < K;
        #pragma unroll
        for (int r = 0; r < 8; ++r)
            As[kk][q + (r << 4)] = kval ? Ab[(size_t)(q + (r << 4)) * K + kidx] : 0.f;
        #pragma unroll
        for (int r = 0; r < 4; ++r) {
            int g = n0 + q + (r << 4);
            Wsh[kk][q + (r << 4)] = (kval && g < G4) ? W[(size_t)g * K + kidx] : 0.f;
        }
        __syncthreads();
        #pragma unroll
        for (int k = 0; k < 16; ++k) {
            float a[8], wv[4];
            #pragma unroll
            for (int i = 0; i < 8; ++i) a[i] = As[k][ty + (i << 4)];
            #pragma unroll
            for (int j = 0; j < 4; ++j) wv[j] = Wsh[k][(tx << 2) + j];
            #pragma unroll
            for (int i = 0; i < 8; ++i)
                #pragma unroll
                for (int j = 0; j < 4; ++j) acc[i][j] = fmaf(a[i], wv[j], acc[i][j]);
        }
        __syncthreads();
    }
    #pragma unroll
    for (int i = 0; i < 8; ++i) {
        #pragma unroll
        for (int j = 0; j < 4; ++j) {
            int g = n0 + (tx << 2) + j;
            if (g < G4) Cb[(size_t)(ty + (i << 4)) * G4 + g] = acc[i][j] + bsum[g];
        }
    }
}

// ---------------- LSTM recurrent scan over one 128-step chunk: one WG per batch ----------------
// preC: (B, CH, 720); whhT: (180, 720); hout: (B, S, 180); hst/cst: (B, 180)
__global__ __launch_bounds__(384) void lstm_scan(const float* __restrict__ preC,
                                                 const float* __restrict__ whhT,
                                                 float* __restrict__ hout, int t0,
                                                 float* __restrict__ hst,
                                                 float* __restrict__ cst) {
    int b = blockIdx.x, tid = threadIdx.x;
    __shared__ float h[HH];
    __shared__ float gates[G4];
    float c = 0.f;
    if (tid < HH) {
        if (t0 == 0) { h[tid] = 0.f; }
        else { h[tid] = hst[b * HH + tid]; c = cst[b * HH + tid]; }
    }
    __syncthreads();
    const float* preb = preC + (size_t)b * CH * G4;
    for (int t = 0; t < CH; ++t) {
        if (tid < 360) {
            const float* pp = preb + (size_t)t * G4 + 2 * tid;
            float2 acc = *(const float2*)pp;
            const float* wp = whhT + 2 * tid;
            #pragma unroll 4
            for (int k = 0; k < HH; ++k) {
                float2 w2 = *(const float2*)(wp + (size_t)k * G4);
                float hk = h[k];
                acc.x = fmaf(hk, w2.x, acc.x);
                acc.y = fmaf(hk, w2.y, acc.y);
            }
            gates[2 * tid] = acc.x;
            gates[2 * tid + 1] = acc.y;
        }
        __syncthreads();
        if (tid < HH) {
            float gi = gates[tid], gf = gates[HH + tid], gg = gates[2 * HH + tid], go = gates[3 * HH + tid];
            float si = 1.f / (1.f + __expf(-gi));
            float sf = 1.f / (1.f + __expf(-gf));
            float so = 1.f / (1.f + __expf(-go));
            float tg = tanhf(gg);
            c = sf * c + si * tg;
            float hn = so * tanhf(c);
            h[tid] = hn;
            hout[((size_t)b * SS + t0 + t) * HH + tid] = hn;
        }
        __syncthreads();
    }
    if (tid < HH) { hst[b * HH + tid] = h[tid]; cst[b * HH + tid] = c; }
}

// ---------------- epilogue ----------------
__global__ void gather_last(const float* __restrict__ hfin, const int* __restrict__ lens,
                            float* __restrict__ last) {
    int idx = blockIdx.x * blockDim.x + threadIdx.x;
    if (idx >= BB * HH) return;
    int b = idx / HH, d = idx % HH;
    int t = lens[b] - 1;
    t = t < 0 ? 0 : (t > SS - 1 ? SS - 1 : t);
    last[idx] = hfin[((size_t)b * SS + t) * HH + d];
}

__global__ __launch_bounds__(256) void post_kernel(const float* __restrict__ last,
                                                   const float* __restrict__ pw,  // (8192,180)
                                                   const float* __restrict__ pb,
                                                   float* __restrict__ post) {
    int b = blockIdx.x, tid = threadIdx.x;
    __shared__ float lb[HH];
    if (tid < HH) lb[tid] = last[b * HH + tid];
    __syncthreads();
    const float4* lb4 = (const float4*)lb;
    for (int p = tid; p < NPOST; p += 256) {
        const float4* wr = (const float4*)(pw + (size_t)p * HH);
        float acc = pb[p];
        #pragma unroll 5
        for (int kk = 0; kk < HH / 4; ++kk) {
            float4 w = wr[kk]; float4 l = lb4[kk];
            acc += w.x * l.x + w.y * l.y + w.z * l.z + w.w * l.w;
        }
        post[(size_t)b * NPOST + p] = acc > 0.f ? acc : 0.01f * acc;
    }
}

__global__ __launch_bounds__(256) void up_kernel(const float* __restrict__ post,
                                                 const float* __restrict__ uw,  // (300,8192)
                                                 const float* __restrict__ ub,
                                                 float* __restrict__ out) {
    int b = blockIdx.x, tid = threadIdx.x;
    __shared__ float pl[NPOST];  // 32 KB
    for (int i = tid; i < NPOST; i += 256) pl[i] = post[(size_t)b * NPOST + i];
    __syncthreads();
    const float4* pl4 = (const float4*)pl;
    for (int o = tid; o < NOUT; o += 256) {
        const float4* wr = (const float4*)(uw + (size_t)o * NPOST);
        float acc = ub[o];
        for (int kk = 0; kk < NPOST / 4; ++kk) {
            float4 w = wr[kk]; float4 p4 = pl4[kk];
            acc += w.x * p4.x + w.y * p4.y + w.z * p4.z + w.w * p4.w;
        }
        out[(size_t)b * NOUT + o] = acc;
    }
}

extern "C" void kernel_launch(void* const* d_in, const int* in_sizes, int n_in,
                              void* d_out, int out_size, void* d_ws, size_t ws_size,
                              hipStream_t stream) {
    const float* x        = (const float*)d_in[0];
    const int*   lens     = (const int*)d_in[1];
    const float* conv_w   = (const float*)d_in[2];
    const float* conv_b   = (const float*)d_in[3];
    const float* wih0     = (const float*)d_in[4];
    const float* wih_rest = (const float*)d_in[5];
    const float* whh      = (const float*)d_in[6];
    const float* bih      = (const float*)d_in[7];
    const float* bhh      = (const float*)d_in[8];
    const float* post_w   = (const float*)d_in[9];
    const float* post_b   = (const float*)d_in[10];
    const float* up_w     = (const float*)d_in[11];
    const float* up_b     = (const float*)d_in[12];
    float* out = (float*)d_out;

    // workspace layout (~123 MB total)
    char* ws = (char*)d_ws;
    size_t off = 0;
    auto alloc = [&](size_t bytes) -> void* {
        void* p = ws + off;
        off = (off + bytes + 255) & ~(size_t)255;
        return p;
    };
    float* bufA  = (float*)alloc((size_t)BB * SS * HH * 4);   // 47.2 MB (mel ping + h ping)
    float* bufB  = (float*)alloc((size_t)BB * SS * HH * 4);   // 47.2 MB (mel pong + h pong)
    float* preC  = (float*)alloc((size_t)BB * CH * G4 * 4);   // 23.6 MB
    float* whhT  = (float*)alloc((size_t)NL * HH * G4 * 4);   // 2.07 MB
    float* bsum  = (float*)alloc((size_t)NL * G4 * 4);
    float* hst   = (float*)alloc((size_t)BB * HH * 4);
    float* cst   = (float*)alloc((size_t)BB * HH * 4);
    float* lastb = (float*)alloc((size_t)BB * HH * 4);
    float* postb = (float*)alloc((size_t)BB * NPOST * 4);     // 2.1 MB
    (void)ws_size; (void)in_sizes; (void)n_in; (void)out_size;

    prep_whhT<<<(NL * G4 * HH + 255) / 256, 256, 0, stream>>>(whh, whhT);
    prep_bsum<<<(NL * G4 + 255) / 256, 256, 0, stream>>>(bih, bhh, bsum);

    // 3 residual mel-smooth blocks (ping-pong in bufA/bufB)
    mel_block<<<dim3(BB, SS / TT), 256, 0, stream>>>(x, bufA, conv_w + 0 * 900, conv_b + 0 * 60);
    mel_block<<<dim3(BB, SS / TT), 256, 0, stream>>>(bufA, bufB, conv_w + 1 * 900, conv_b + 1 * 60);
    mel_block<<<dim3(BB, SS / TT), 256, 0, stream>>>(bufB, bufA, conv_w + 2 * 900, conv_b + 2 * 60);

    // 4 LSTM layers, time-chunked: gemm chunk -> scan chunk
    const float* cur = bufA;            // mel output (B,S,60)
    float* houts[NL] = {bufB, bufA, bufB, bufA};
    for (int l = 0; l < NL; ++l) {
        const float* wih = (l == 0) ? wih0 : (wih_rest + (size_t)(l - 1) * G4 * HH);
        int K = (l == 0) ? MEL : HH;
        for (int t0 = 0; t0 < SS; t0 += CH) {
            gemm_pre<<<dim3(BB, 12), 256, 0, stream>>>(cur, K, t0, wih, bsum + l * G4, preC);
            lstm_scan<<<BB, 384, 0, stream>>>(preC, whhT + (size_t)l * HH * G4,
                                              houts[l], t0, hst, cst);
        }
        cur = houts[l];
    }

    gather_last<<<(BB * HH + 255) / 256, 256, 0, stream>>>(cur, lens, lastb);
    post_kernel<<<BB, 256, 0, stream>>>(lastb, post_w, post_b, postb);
    up_kernel<<<BB, 256, 0, stream>>>(postb, up_w, up_b, out);
}

// Round 3
// 31487.424 us; speedup vs baseline: 1.1024x; 1.1024x over previous
//
#include <hip/hip_runtime.h>
#include <hip/hip_bf16.h>

#define BB 64
#define SS 1024
#define MEL 60
#define HH 180
#define G4 720   // 4*H
#define KP 192   // padded K (h) dimension for the recurrent matvec
#define NL 4
#define NPOST 8192
#define NOUT 300
#define TT 128   // mel time tile
#define CH 128   // lstm time chunk
#define PF 24    // weight prefetch depth (KP/PF = 8 blocks)

// ---------------- prep kernels ----------------
// whhT[l][k][g] = whh[l][g][k] for k<180, 0 for 180<=k<192
__global__ void prep_whhT(const float* __restrict__ whh, float* __restrict__ whhT) {
    int idx = blockIdx.x * blockDim.x + threadIdx.x;
    int total = NL * KP * G4;
    if (idx >= total) return;
    int l = idx / (KP * G4);
    int rem = idx % (KP * G4);
    int k = rem / G4;
    int g = rem % G4;
    whhT[idx] = (k < HH) ? whh[((size_t)l * G4 + g) * HH + k] : 0.f;
}

__global__ void prep_bsum(const float* __restrict__ bih, const float* __restrict__ bhh,
                          float* __restrict__ bsum) {
    int idx = blockIdx.x * blockDim.x + threadIdx.x;
    if (idx >= NL * G4) return;
    bsum[idx] = bih[idx] + bhh[idx];
}

// ---------------- mel smooth residual block ----------------
__global__ __launch_bounds__(256) void mel_block(const float* __restrict__ in,
                                                 float* __restrict__ out,
                                                 const float* __restrict__ w,   // (3,20,3,5)
                                                 const float* __restrict__ bias) { // (3,20)
    __shared__ float xt[TT + 4][MEL];
    __shared__ float ws[900];
    __shared__ float bs[MEL];
    int bb = blockIdx.x;
    int t0 = blockIdx.y * TT;
    int tid = threadIdx.x;
    const float* inb = in + (size_t)bb * SS * MEL;
    for (int idx = tid; idx < (TT + 4) * MEL; idx += 256) {
        int tt = idx / MEL, ch = idx % MEL;
        int t = t0 + tt - 2;
        xt[tt][ch] = (t >= 0 && t < SS) ? inb[(size_t)t * MEL + ch] : 0.f;
    }
    for (int idx = tid; idx < 900; idx += 256) ws[idx] = w[idx];
    if (tid < MEL) bs[tid] = bias[(tid % 3) * 20 + tid / 3];  // out ch 3i+j gets b[j][i]
    __syncthreads();
    for (int idx = tid; idx < TT * MEL; idx += 256) {
        int tt = idx / MEL, ch = idx % MEL;
        int i = ch / 3, j = ch % 3;
        int qb = 3 * i + (j - 1);
        float acc = bs[ch];
        #pragma unroll
        for (int c = 0; c < 3; ++c) {
            int q = qb + c;
            if (q >= 0 && q < MEL) {
                const float* wp = ws + ((j * 20 + i) * 3 + c) * 5;
                #pragma unroll
                for (int k = 0; k < 5; ++k) acc += xt[tt + k][q] * wp[k];
            }
        }
        out[(size_t)bb * SS * MEL + (size_t)(t0 + tt) * MEL + ch] = acc + xt[tt + 2][ch];
    }
}

// ---------------- input GEMM (chunked): one block-col = one batch's 128-step chunk ----------------
__global__ __launch_bounds__(256) void gemm_pre(const float* __restrict__ A, int K, int t0,
                                                const float* __restrict__ W,
                                                const float* __restrict__ bsum,
                                                float* __restrict__ C) {
    __shared__ float As[16][132];
    __shared__ float Wsh[16][68];
    const float* Ab = A + ((size_t)blockIdx.x * SS + t0) * K;
    float* Cb = C + (size_t)blockIdx.x * CH * G4;
    int n0 = blockIdx.y * 64;
    int tid = threadIdx.x;
    int kk = tid & 15, q = tid >> 4;
    int tx = tid & 15, ty = tid >> 4;
    float acc[8][4];
    #pragma unroll
    for (int i = 0; i < 8; ++i)
        #pragma unroll
        for (int j = 0; j < 4; ++j) acc[i][j] = 0.f;

    int ktiles = (K + 15) / 16;
    for (int kt = 0; kt < ktiles; ++kt) {
        int kidx = kt * 16 + kk;
        bool kval = kidx < K;
        #pragma unroll
        for (int r = 0; r < 8; ++r)
            As[kk][q + (r << 4)] = kval ? Ab[(size_t)(q + (r << 4)) * K + kidx] : 0.f;
        #pragma unroll
        for (int r = 0; r < 4; ++r) {
            int g = n0 + q + (r << 4);
            Wsh[kk][q + (r << 4)] = (kval && g < G4) ? W[(size_t)g * K + kidx] : 0.f;
        }
        __syncthreads();
        #pragma unroll
        for (int k = 0; k < 16; ++k) {
            float a[8], wv[4];
            #pragma unroll
            for (int i = 0; i < 8; ++i) a[i] = As[k][ty + (i << 4)];
            #pragma unroll
            for (int j = 0; j < 4; ++j) wv[j] = Wsh[k][(tx << 2) + j];
            #pragma unroll
            for (int i = 0; i < 8; ++i)
                #pragma unroll
                for (int j = 0; j < 4; ++j) acc[i][j] = fmaf(a[i], wv[j], acc[i][j]);
        }
        __syncthreads();
    }
    #pragma unroll
    for (int i = 0; i < 8; ++i) {
        #pragma unroll
        for (int j = 0; j < 4; ++j) {
            int g = n0 + (tx << 2) + j;
            if (g < G4) Cb[(size_t)(ty + (i << 4)) * G4 + g] = acc[i][j] + bsum[g];
        }
    }
}

// ---------------- LSTM recurrent scan over one 128-step chunk ----------------
// one WG (768 thr) per batch; thread g owns gate column g; weights streamed from L2
// with PF-deep prefetch; whhT is (KP=192, 720) zero-padded.
__global__ __launch_bounds__(768) void lstm_scan(const float* __restrict__ preC,
                                                 const float* __restrict__ whhT,
                                                 float* __restrict__ hout, int t0,
                                                 float* __restrict__ hst,
                                                 float* __restrict__ cst) {
    int b = blockIdx.x, tid = threadIdx.x;
    __shared__ float h[KP];
    __shared__ float gates[G4];
    float c = 0.f;
    if (tid < KP) h[tid] = 0.f;
    if (tid < HH && t0 > 0) { h[tid] = hst[b * HH + tid]; c = cst[b * HH + tid]; }
    __syncthreads();
    const float* preb = preC + (size_t)b * CH * G4;
    const float* wp = whhT + tid;   // column g = tid, row stride G4
    for (int t = 0; t < CH; ++t) {
        if (tid < G4) {
            float a0 = preb[(size_t)t * G4 + tid];
            float a1 = 0.f, a2 = 0.f, a3 = 0.f;
            float wb[PF], wn[PF];
            #pragma unroll
            for (int i = 0; i < PF; ++i) wb[i] = wp[(size_t)i * G4];
            #pragma unroll 1
            for (int kb = 0; kb < KP; kb += PF) {
                if (kb + PF < KP) {
                    #pragma unroll
                    for (int i = 0; i < PF; ++i) wn[i] = wp[(size_t)(kb + PF + i) * G4];
                }
                const float4* h4 = (const float4*)&h[kb];
                #pragma unroll
                for (int ii = 0; ii < PF / 4; ++ii) {
                    float4 hv = h4[ii];
                    a0 = fmaf(hv.x, wb[4 * ii + 0], a0);
                    a1 = fmaf(hv.y, wb[4 * ii + 1], a1);
                    a2 = fmaf(hv.z, wb[4 * ii + 2], a2);
                    a3 = fmaf(hv.w, wb[4 * ii + 3], a3);
                }
                if (kb + PF < KP) {
                    #pragma unroll
                    for (int i = 0; i < PF; ++i) wb[i] = wn[i];
                }
            }
            gates[tid] = (a0 + a1) + (a2 + a3);
        }
        __syncthreads();
        if (tid < HH) {
            float gi = gates[tid], gf = gates[HH + tid], gg = gates[2 * HH + tid], go = gates[3 * HH + tid];
            float si = 1.f / (1.f + __expf(-gi));
            float sf = 1.f / (1.f + __expf(-gf));
            float so = 1.f / (1.f + __expf(-go));
            float tg = tanhf(gg);
            c = sf * c + si * tg;
            float hn = so * tanhf(c);
            h[tid] = hn;
            hout[((size_t)b * SS + t0 + t) * HH + tid] = hn;
        }
        __syncthreads();
    }
    if (tid < HH) { hst[b * HH + tid] = h[tid]; cst[b * HH + tid] = c; }
}

// ---------------- epilogue ----------------
__global__ void gather_last(const float* __restrict__ hfin, const int* __restrict__ lens,
                            float* __restrict__ last) {
    int idx = blockIdx.x * blockDim.x + threadIdx.x;
    if (idx >= BB * HH) return;
    int b = idx / HH, d = idx % HH;
    int t = lens[b] - 1;
    t = t < 0 ? 0 : (t > SS - 1 ? SS - 1 : t);
    last[idx] = hfin[((size_t)b * SS + t) * HH + d];
}

__global__ __launch_bounds__(256) void post_kernel(const float* __restrict__ last,
                                                   const float* __restrict__ pw,  // (8192,180)
                                                   const float* __restrict__ pb,
                                                   float* __restrict__ post) {
    int b = blockIdx.x, tid = threadIdx.x;
    __shared__ float lb[HH];
    if (tid < HH) lb[tid] = last[b * HH + tid];
    __syncthreads();
    const float4* lb4 = (const float4*)lb;
    for (int p = tid; p < NPOST; p += 256) {
        const float4* wr = (const float4*)(pw + (size_t)p * HH);
        float acc = pb[p];
        #pragma unroll 5
        for (int kk = 0; kk < HH / 4; ++kk) {
            float4 w = wr[kk]; float4 l = lb4[kk];
            acc += w.x * l.x + w.y * l.y + w.z * l.z + w.w * l.w;
        }
        post[(size_t)b * NPOST + p] = acc > 0.f ? acc : 0.01f * acc;
    }
}

__global__ __launch_bounds__(256) void up_kernel(const float* __restrict__ post,
                                                 const float* __restrict__ uw,  // (300,8192)
                                                 const float* __restrict__ ub,
                                                 float* __restrict__ out) {
    int b = blockIdx.x, tid = threadIdx.x;
    __shared__ float pl[NPOST];  // 32 KB
    for (int i = tid; i < NPOST; i += 256) pl[i] = post[(size_t)b * NPOST + i];
    __syncthreads();
    const float4* pl4 = (const float4*)pl;
    for (int o = tid; o < NOUT; o += 256) {
        const float4* wr = (const float4*)(uw + (size_t)o * NPOST);
        float acc = ub[o];
        for (int kk = 0; kk < NPOST / 4; ++kk) {
            float4 w = wr[kk]; float4 p4 = pl4[kk];
            acc += w.x * p4.x + w.y * p4.y + w.z * p4.z + w.w * p4.w;
        }
        out[(size_t)b * NOUT + o] = acc;
    }
}

extern "C" void kernel_launch(void* const* d_in, const int* in_sizes, int n_in,
                              void* d_out, int out_size, void* d_ws, size_t ws_size,
                              hipStream_t stream) {
    const float* x        = (const float*)d_in[0];
    const int*   lens     = (const int*)d_in[1];
    const float* conv_w   = (const float*)d_in[2];
    const float* conv_b   = (const float*)d_in[3];
    const float* wih0     = (const float*)d_in[4];
    const float* wih_rest = (const float*)d_in[5];
    const float* whh      = (const float*)d_in[6];
    const float* bih      = (const float*)d_in[7];
    const float* bhh      = (const float*)d_in[8];
    const float* post_w   = (const float*)d_in[9];
    const float* post_b   = (const float*)d_in[10];
    const float* up_w     = (const float*)d_in[11];
    const float* up_b     = (const float*)d_in[12];
    float* out = (float*)d_out;

    // workspace layout (~124 MB total)
    char* ws = (char*)d_ws;
    size_t off = 0;
    auto alloc = [&](size_t bytes) -> void* {
        void* p = ws + off;
        off = (off + bytes + 255) & ~(size_t)255;
        return p;
    };
    float* bufA  = (float*)alloc((size_t)BB * SS * HH * 4);   // 47.2 MB
    float* bufB  = (float*)alloc((size_t)BB * SS * HH * 4);   // 47.2 MB
    float* preC  = (float*)alloc((size_t)BB * CH * G4 * 4);   // 23.6 MB
    float* whhT  = (float*)alloc((size_t)NL * KP * G4 * 4);   // 2.2 MB (K-padded)
    float* bsum  = (float*)alloc((size_t)NL * G4 * 4);
    float* hst   = (float*)alloc((size_t)BB * HH * 4);
    float* cst   = (float*)alloc((size_t)BB * HH * 4);
    float* lastb = (float*)alloc((size_t)BB * HH * 4);
    float* postb = (float*)alloc((size_t)BB * NPOST * 4);     // 2.1 MB
    (void)ws_size; (void)in_sizes; (void)n_in; (void)out_size;

    prep_whhT<<<(NL * KP * G4 + 255) / 256, 256, 0, stream>>>(whh, whhT);
    prep_bsum<<<(NL * G4 + 255) / 256, 256, 0, stream>>>(bih, bhh, bsum);

    // 3 residual mel-smooth blocks (ping-pong in bufA/bufB)
    mel_block<<<dim3(BB, SS / TT), 256, 0, stream>>>(x, bufA, conv_w + 0 * 900, conv_b + 0 * 60);
    mel_block<<<dim3(BB, SS / TT), 256, 0, stream>>>(bufA, bufB, conv_w + 1 * 900, conv_b + 1 * 60);
    mel_block<<<dim3(BB, SS / TT), 256, 0, stream>>>(bufB, bufA, conv_w + 2 * 900, conv_b + 2 * 60);

    // 4 LSTM layers, time-chunked: gemm chunk -> scan chunk
    const float* cur = bufA;            // mel output (B,S,60)
    float* houts[NL] = {bufB, bufA, bufB, bufA};
    for (int l = 0; l < NL; ++l) {
        const float* wih = (l == 0) ? wih0 : (wih_rest + (size_t)(l - 1) * G4 * HH);
        int K = (l == 0) ? MEL : HH;
        for (int t0 = 0; t0 < SS; t0 += CH) {
            gemm_pre<<<dim3(BB, 12), 256, 0, stream>>>(cur, K, t0, wih, bsum + l * G4, preC);
            lstm_scan<<<BB, 768, 0, stream>>>(preC, whhT + (size_t)l * KP * G4,
                                              houts[l], t0, hst, cst);
        }
        cur = houts[l];
    }

    gather_last<<<(BB * HH + 255) / 256, 256, 0, stream>>>(cur, lens, lastb);
    post_kernel<<<BB, 256, 0, stream>>>(lastb, post_w, post_b, postb);
    up_kernel<<<BB, 256, 0, stream>>>(postb, up_w, up_b, out);
}

// Round 4
// 3532.570 us; speedup vs baseline: 9.8260x; 8.9135x over previous
//
#include <hip/hip_runtime.h>
#include <hip/hip_fp16.h>

#define BB 64
#define SS 1024
#define MEL 60
#define HH 180
#define G4 720   // 4*H
#define KP 192   // padded K (h) dim: 24 blocks of 8
#define NL 4
#define NPOST 8192
#define NOUT 300
#define TT 128   // mel time tile
#define CH 64    // lstm time chunk
#define NCH (SS / CH)

#if defined(__has_builtin)
#if __has_builtin(__builtin_amdgcn_fdot2)
#define HAVE_FDOT2 1
#endif
#endif
#ifndef HAVE_FDOT2
#define HAVE_FDOT2 0
#endif

__device__ __forceinline__ float fdot2u(unsigned int w, unsigned int h, float acc) {
#if HAVE_FDOT2
    typedef _Float16 h2_t __attribute__((ext_vector_type(2)));
    union U { unsigned int u; h2_t v; };
    U a, b;
    a.u = w; b.u = h;
    return __builtin_amdgcn_fdot2(a.v, b.v, acc, false);
#else
    __half2 aw = *reinterpret_cast<const __half2*>(&w);
    __half2 ah = *reinterpret_cast<const __half2*>(&h);
    acc += __half2float(__low2half(aw)) * __half2float(__low2half(ah));
    acc += __half2float(__high2half(aw)) * __half2float(__high2half(ah));
    return acc;
#endif
}

// ---------------- prep ----------------
// w16 layout: [l][k8][g][jj] ushort, element = f16(whh[l][g][8*k8+jj]), zero-padded k>=180
__global__ void prep_w16(const float* __restrict__ whh, unsigned short* __restrict__ w16) {
    int idx = blockIdx.x * blockDim.x + threadIdx.x;
    int total = NL * KP * G4;
    if (idx >= total) return;
    int l = idx / (KP * G4);
    int r = idx % (KP * G4);
    int k8 = r / (G4 * 8);
    int r2 = r % (G4 * 8);
    int g = r2 / 8, jj = r2 % 8;
    int k = 8 * k8 + jj;
    float v = (k < HH) ? whh[((size_t)l * G4 + g) * HH + k] : 0.f;
    w16[idx] = __half_as_ushort(__float2half(v));
}

__global__ void prep_bsum(const float* __restrict__ bih, const float* __restrict__ bhh,
                          float* __restrict__ bsum) {
    int idx = blockIdx.x * blockDim.x + threadIdx.x;
    if (idx >= NL * G4) return;
    bsum[idx] = bih[idx] + bhh[idx];
}

// ---------------- mel smooth residual block ----------------
template <typename TIN>
__global__ __launch_bounds__(256) void mel_block(const TIN* __restrict__ in,
                                                 __half* __restrict__ out,
                                                 const float* __restrict__ w,   // (3,20,3,5)
                                                 const float* __restrict__ bias) { // (3,20)
    __shared__ float xt[TT + 4][MEL];
    __shared__ float ws[900];
    __shared__ float bs[MEL];
    int bb = blockIdx.x;
    int t0 = blockIdx.y * TT;
    int tid = threadIdx.x;
    const TIN* inb = in + (size_t)bb * SS * MEL;
    for (int idx = tid; idx < (TT + 4) * MEL; idx += 256) {
        int tt = idx / MEL, ch = idx % MEL;
        int t = t0 + tt - 2;
        xt[tt][ch] = (t >= 0 && t < SS) ? (float)inb[(size_t)t * MEL + ch] : 0.f;
    }
    for (int idx = tid; idx < 900; idx += 256) ws[idx] = w[idx];
    if (tid < MEL) bs[tid] = bias[(tid % 3) * 20 + tid / 3];  // out ch 3i+j gets b[j][i]
    __syncthreads();
    for (int idx = tid; idx < TT * MEL; idx += 256) {
        int tt = idx / MEL, ch = idx % MEL;
        int i = ch / 3, j = ch % 3;
        int qb = 3 * i + (j - 1);
        float acc = bs[ch];
        #pragma unroll
        for (int c = 0; c < 3; ++c) {
            int q = qb + c;
            if (q >= 0 && q < MEL) {
                const float* wp = ws + ((j * 20 + i) * 3 + c) * 5;
                #pragma unroll
                for (int k = 0; k < 5; ++k) acc += xt[tt + k][q] * wp[k];
            }
        }
        out[(size_t)bb * SS * MEL + (size_t)(t0 + tt) * MEL + ch] =
            __float2half(acc + xt[tt + 2][ch]);
    }
}

// ---------------- multi-job input GEMM: 64 rows (one chunk) per block-row ----------------
struct GemmArgs {
    const __half* A[NL];
    const float* W[NL];
    const float* bs[NL];
    float* C[NL];
    int K[NL];
    int t0[NL];
};

__global__ __launch_bounds__(256) void gemm_pre(GemmArgs ga) {
    int j = blockIdx.z;
    int K = ga.K[j];
    const __half* Ab = ga.A[j] + ((size_t)blockIdx.x * SS + ga.t0[j]) * K;
    float* Cb = ga.C[j] + (size_t)blockIdx.x * CH * G4;
    const float* W = ga.W[j];
    const float* bsum = ga.bs[j];
    __shared__ float As[16][68];
    __shared__ float Wsh[16][68];
    int n0 = blockIdx.y * 64;
    int tid = threadIdx.x;
    int kk = tid & 15, q = tid >> 4;
    int tx = tid & 15, ty = tid >> 4;
    float acc[4][4];
    #pragma unroll
    for (int i = 0; i < 4; ++i)
        #pragma unroll
        for (int jj = 0; jj < 4; ++jj) acc[i][jj] = 0.f;

    int ktiles = (K + 15) / 16;
    for (int kt = 0; kt < ktiles; ++kt) {
        int kidx = kt * 16 + kk;
        bool kval = kidx < K;
        #pragma unroll
        for (int r = 0; r < 4; ++r)
            As[kk][q + (r << 4)] = kval ? __half2float(Ab[(size_t)(q + (r << 4)) * K + kidx]) : 0.f;
        #pragma unroll
        for (int r = 0; r < 4; ++r) {
            int g = n0 + q + (r << 4);
            Wsh[kk][q + (r << 4)] = (kval && g < G4) ? W[(size_t)g * K + kidx] : 0.f;
        }
        __syncthreads();
        #pragma unroll
        for (int k = 0; k < 16; ++k) {
            float a[4], wv[4];
            #pragma unroll
            for (int i = 0; i < 4; ++i) a[i] = As[k][ty + (i << 4)];
            #pragma unroll
            for (int jj = 0; jj < 4; ++jj) wv[jj] = Wsh[k][(tx << 2) + jj];
            #pragma unroll
            for (int i = 0; i < 4; ++i)
                #pragma unroll
                for (int jj = 0; jj < 4; ++jj) acc[i][jj] = fmaf(a[i], wv[jj], acc[i][jj]);
        }
        __syncthreads();
    }
    #pragma unroll
    for (int i = 0; i < 4; ++i) {
        #pragma unroll
        for (int jj = 0; jj < 4; ++jj) {
            int g = n0 + (tx << 2) + jj;
            if (g < G4) Cb[(size_t)(ty + (i << 4)) * G4 + g] = acc[i][jj] + bsum[g];
        }
    }
}

// ---------------- multi-job LSTM scan: weights resident in VGPRs (f16 packed) ----------------
struct ScanArgs {
    const float* pre[NL];
    const unsigned short* w4[NL];
    __half* hout[NL];
    float* hst[NL];
    float* cst[NL];
    int t0[NL];
};

__global__ __launch_bounds__(768, 3) void lstm_scan(ScanArgs sa) {
    int j = blockIdx.x / BB, b = blockIdx.x % BB;
    int tid = threadIdx.x;
    int t0 = sa.t0[j];
    const float* preb = sa.pre[j] + (size_t)b * CH * G4;
    const uint4* w4 = (const uint4*)sa.w4[j];
    __half* houtb = sa.hout[j] + ((size_t)b * SS + (size_t)t0) * HH;
    float* hstb = sa.hst[j] + b * HH;
    float* cstb = sa.cst[j] + b * HH;

    __shared__ __align__(16) unsigned short hs[KP];  // h state as f16
    __shared__ float gates[G4];

    // entire per-column recurrent weight slice -> 24 uint4 = 96 VGPRs, loaded once
    uint4 wreg[24];
    if (tid < G4) {
        #pragma unroll
        for (int k8 = 0; k8 < 24; ++k8) wreg[k8] = w4[k8 * G4 + tid];
    }
    float c = 0.f;
    if (tid < KP) {
        float hv = 0.f;
        if (t0 > 0 && tid < HH) { hv = hstb[tid]; c = cstb[tid]; }
        hs[tid] = __half_as_ushort(__float2half(hv));
    }
    __syncthreads();

    float pre_cur = (tid < G4) ? preb[tid] : 0.f;
    float hlast = 0.f;
    for (int t = 0; t < CH; ++t) {
        float pre_nxt = 0.f;
        if (tid < G4 && t + 1 < CH) pre_nxt = preb[(size_t)(t + 1) * G4 + tid];
        if (tid < G4) {
            float acc = pre_cur;
            const uint4* hv4 = (const uint4*)hs;
            #pragma unroll
            for (int k8 = 0; k8 < 24; ++k8) {
                uint4 h8 = hv4[k8];
                uint4 w8 = wreg[k8];
                acc = fdot2u(w8.x, h8.x, acc);
                acc = fdot2u(w8.y, h8.y, acc);
                acc = fdot2u(w8.z, h8.z, acc);
                acc = fdot2u(w8.w, h8.w, acc);
            }
            gates[tid] = acc;
        }
        __syncthreads();
        if (tid < HH) {
            float gi = gates[tid], gf = gates[HH + tid];
            float gg = gates[2 * HH + tid], go = gates[3 * HH + tid];
            float si = 1.f / (1.f + __expf(-gi));
            float sf = 1.f / (1.f + __expf(-gf));
            float so = 1.f / (1.f + __expf(-go));
            float tg = 1.f - 2.f / (__expf(2.f * gg) + 1.f);   // tanh
            c = sf * c + si * tg;
            float hn = so * (1.f - 2.f / (__expf(2.f * c) + 1.f));
            __half hh = __float2half(hn);
            hs[tid] = __half_as_ushort(hh);
            hlast = __half2float(hh);
            houtb[(size_t)t * HH + tid] = hh;
        }
        __syncthreads();
        pre_cur = pre_nxt;
    }
    if (tid < HH) { hstb[tid] = hlast; cstb[tid] = c; }
}

// ---------------- epilogue ----------------
__global__ void gather_last(const __half* __restrict__ hfin, const int* __restrict__ lens,
                            float* __restrict__ last) {
    int idx = blockIdx.x * blockDim.x + threadIdx.x;
    if (idx >= BB * HH) return;
    int b = idx / HH, d = idx % HH;
    int t = lens[b] - 1;
    t = t < 0 ? 0 : (t > SS - 1 ? SS - 1 : t);
    last[idx] = __half2float(hfin[((size_t)b * SS + t) * HH + d]);
}

__global__ __launch_bounds__(256) void post_kernel(const float* __restrict__ last,
                                                   const float* __restrict__ pw,  // (8192,180)
                                                   const float* __restrict__ pb,
                                                   float* __restrict__ post) {
    int b = blockIdx.x, tid = threadIdx.x;
    __shared__ float lb[HH];
    if (tid < HH) lb[tid] = last[b * HH + tid];
    __syncthreads();
    const float4* lb4 = (const float4*)lb;
    for (int p = tid; p < NPOST; p += 256) {
        const float4* wr = (const float4*)(pw + (size_t)p * HH);
        float acc = pb[p];
        #pragma unroll 5
        for (int kk = 0; kk < HH / 4; ++kk) {
            float4 w = wr[kk]; float4 l = lb4[kk];
            acc += w.x * l.x + w.y * l.y + w.z * l.z + w.w * l.w;
        }
        post[(size_t)b * NPOST + p] = acc > 0.f ? acc : 0.01f * acc;
    }
}

__global__ __launch_bounds__(256) void up_kernel(const float* __restrict__ post,
                                                 const float* __restrict__ uw,  // (300,8192)
                                                 const float* __restrict__ ub,
                                                 float* __restrict__ out) {
    int b = blockIdx.x, tid = threadIdx.x;
    __shared__ float pl[NPOST];  // 32 KB
    for (int i = tid; i < NPOST; i += 256) pl[i] = post[(size_t)b * NPOST + i];
    __syncthreads();
    const float4* pl4 = (const float4*)pl;
    for (int o = tid; o < NOUT; o += 256) {
        const float4* wr = (const float4*)(uw + (size_t)o * NPOST);
        float acc = ub[o];
        for (int kk = 0; kk < NPOST / 4; ++kk) {
            float4 w = wr[kk]; float4 p4 = pl4[kk];
            acc += w.x * p4.x + w.y * p4.y + w.z * p4.z + w.w * p4.w;
        }
        out[(size_t)b * NOUT + o] = acc;
    }
}

extern "C" void kernel_launch(void* const* d_in, const int* in_sizes, int n_in,
                              void* d_out, int out_size, void* d_ws, size_t ws_size,
                              hipStream_t stream) {
    const float* x        = (const float*)d_in[0];
    const int*   lens     = (const int*)d_in[1];
    const float* conv_w   = (const float*)d_in[2];
    const float* conv_b   = (const float*)d_in[3];
    const float* wih0     = (const float*)d_in[4];
    const float* wih_rest = (const float*)d_in[5];
    const float* whh      = (const float*)d_in[6];
    const float* bih      = (const float*)d_in[7];
    const float* bhh      = (const float*)d_in[8];
    const float* post_w   = (const float*)d_in[9];
    const float* post_b   = (const float*)d_in[10];
    const float* up_w     = (const float*)d_in[11];
    const float* up_b     = (const float*)d_in[12];
    float* out = (float*)d_out;
    (void)in_sizes; (void)n_in; (void)out_size;

    const size_t szMel   = (size_t)BB * SS * MEL * 2;       // 7.9 MB  (f16)
    const size_t szH     = (size_t)BB * SS * HH * 2;        // 23.6 MB (f16)
    const size_t szPre   = (size_t)BB * CH * G4 * 4;        // 11.8 MB (fp32)
    const size_t szW16   = (size_t)NL * KP * G4 * 2;        // 1.1 MB
    const size_t szBsum  = (size_t)NL * G4 * 4;
    const size_t szState = (size_t)NL * BB * HH * 4;
    const size_t szLast  = (size_t)BB * HH * 4;
    const size_t szPost  = (size_t)BB * NPOST * 4;
    auto pad = [](size_t v) { return (v + 255) & ~(size_t)255; };

    size_t needWF = pad(szMel) + 4 * pad(szH) + 4 * pad(szPre) + pad(szW16) +
                    pad(szBsum) + 2 * pad(szState) + pad(szLast) + pad(szPost) + 4096;
    bool wavefront = ws_size >= needWF;

    char* wsp = (char*)d_ws;
    size_t off = 0;
    auto alloc = [&](size_t bytes) -> void* {
        void* p = wsp + off;
        off = (off + bytes + 255) & ~(size_t)255;
        return p;
    };

    __half* melF = (__half*)alloc(szMel);
    __half* hbuf[NL];
    if (wavefront) {
        for (int l = 0; l < NL; ++l) hbuf[l] = (__half*)alloc(szH);
    } else {
        __half* p0 = (__half*)alloc(szH);
        __half* p1 = (__half*)alloc(szH);
        hbuf[0] = p0; hbuf[1] = p1; hbuf[2] = p0; hbuf[3] = p1;
    }
    float* preC = (float*)alloc(wavefront ? 4 * pad(szPre) : szPre);
    unsigned short* w16 = (unsigned short*)alloc(szW16);
    float* bsum  = (float*)alloc(szBsum);
    float* hstates = (float*)alloc(szState);
    float* cstates = (float*)alloc(szState);
    float* lastb = (float*)alloc(szLast);
    float* postb = (float*)alloc(szPost);

    prep_w16<<<(NL * KP * G4 + 255) / 256, 256, 0, stream>>>(whh, w16);
    prep_bsum<<<(NL * G4 + 255) / 256, 256, 0, stream>>>(bih, bhh, bsum);

    // 3 residual mel-smooth blocks: fp32 in -> f16 chain
    {
        __half* m0 = hbuf[0];  // scratch reuse is safe: consumed before layer0 writes
        __half* m1 = (__half*)((char*)hbuf[0] + pad(szMel));
        mel_block<float><<<dim3(BB, SS / TT), 256, 0, stream>>>(x, m0, conv_w + 0 * 900, conv_b + 0 * 60);
        mel_block<__half><<<dim3(BB, SS / TT), 256, 0, stream>>>(m0, m1, conv_w + 1 * 900, conv_b + 1 * 60);
        mel_block<__half><<<dim3(BB, SS / TT), 256, 0, stream>>>(m1, melF, conv_w + 2 * 900, conv_b + 2 * 60);
    }

    auto fillJob = [&](GemmArgs& ga, ScanArgs& sca, int nj, int l, int c, float* preBase) {
        ga.A[nj]  = (l == 0) ? melF : hbuf[l - 1];
        ga.K[nj]  = (l == 0) ? MEL : HH;
        ga.W[nj]  = (l == 0) ? wih0 : (wih_rest + (size_t)(l - 1) * G4 * HH);
        ga.bs[nj] = bsum + l * G4;
        ga.C[nj]  = preBase;
        ga.t0[nj] = c * CH;
        sca.pre[nj]  = preBase;
        sca.w4[nj]   = w16 + (size_t)l * KP * G4;
        sca.hout[nj] = hbuf[l];
        sca.hst[nj]  = hstates + (size_t)l * BB * HH;
        sca.cst[nj]  = cstates + (size_t)l * BB * HH;
        sca.t0[nj]   = c * CH;
    };

    if (wavefront) {
        for (int w = 0; w < NCH + NL - 1; ++w) {
            GemmArgs ga{}; ScanArgs sca{};
            int nj = 0;
            for (int l = 0; l < NL; ++l) {
                int c = w - l;
                if (c < 0 || c >= NCH) continue;
                float* preBase = (float*)((char*)preC + (size_t)l * pad(szPre));
                fillJob(ga, sca, nj, l, c, preBase);
                ++nj;
            }
            gemm_pre<<<dim3(BB, 12, nj), 256, 0, stream>>>(ga);
            lstm_scan<<<dim3(nj * BB), 768, 0, stream>>>(sca);
        }
    } else {
        for (int l = 0; l < NL; ++l) {
            for (int c = 0; c < NCH; ++c) {
                GemmArgs ga{}; ScanArgs sca{};
                fillJob(ga, sca, 0, l, c, preC);
                gemm_pre<<<dim3(BB, 12, 1), 256, 0, stream>>>(ga);
                lstm_scan<<<dim3(BB), 768, 0, stream>>>(sca);
            }
        }
    }

    gather_last<<<(BB * HH + 255) / 256, 256, 0, stream>>>(hbuf[NL - 1], lens, lastb);
    post_kernel<<<BB, 256, 0, stream>>>(lastb, post_w, post_b, postb);
    up_kernel<<<BB, 256, 0, stream>>>(postb, up_w, up_b, out);
}

// Round 5
// 3122.505 us; speedup vs baseline: 11.1164x; 1.1313x over previous
//
#include <hip/hip_runtime.h>
#include <hip/hip_fp16.h>

#define BB 64
#define SS 1024
#define MEL 60
#define HH 180
#define G4 720   // 4*H
#define KP 192   // padded K (h) dim: 24 blocks of 8
#define NL 4
#define NPOST 8192
#define NOUT 300
#define NOUTP 320  // padded
#define KSPL 16    // K-splits for up gemm
#define TT 128   // mel time tile
#define CH 64    // lstm time chunk
#define NCH (SS / CH)

#if defined(__has_builtin)
#if __has_builtin(__builtin_amdgcn_fdot2)
#define HAVE_FDOT2 1
#endif
#endif
#ifndef HAVE_FDOT2
#define HAVE_FDOT2 0
#endif

__device__ __forceinline__ float fdot2u(unsigned int w, unsigned int h, float acc) {
#if HAVE_FDOT2
    typedef _Float16 h2_t __attribute__((ext_vector_type(2)));
    union U { unsigned int u; h2_t v; };
    U a, b;
    a.u = w; b.u = h;
    return __builtin_amdgcn_fdot2(a.v, b.v, acc, false);
#else
    __half2 aw = *reinterpret_cast<const __half2*>(&w);
    __half2 ah = *reinterpret_cast<const __half2*>(&h);
    acc += __half2float(__low2half(aw)) * __half2float(__low2half(ah));
    acc += __half2float(__high2half(aw)) * __half2float(__high2half(ah));
    return acc;
#endif
}

// ---------------- prep ----------------
// w16 layout: [l][k8][g][jj] ushort, element = f16(whh[l][g][8*k8+jj]), zero-padded k>=180
__global__ void prep_w16(const float* __restrict__ whh, unsigned short* __restrict__ w16) {
    int idx = blockIdx.x * blockDim.x + threadIdx.x;
    int total = NL * KP * G4;
    if (idx >= total) return;
    int l = idx / (KP * G4);
    int r = idx % (KP * G4);
    int k8 = r / (G4 * 8);
    int r2 = r % (G4 * 8);
    int g = r2 / 8, jj = r2 % 8;
    int k = 8 * k8 + jj;
    float v = (k < HH) ? whh[((size_t)l * G4 + g) * HH + k] : 0.f;
    w16[idx] = __half_as_ushort(__float2half(v));
}

__global__ void prep_bsum(const float* __restrict__ bih, const float* __restrict__ bhh,
                          float* __restrict__ bsum) {
    int idx = blockIdx.x * blockDim.x + threadIdx.x;
    if (idx >= NL * G4) return;
    bsum[idx] = bih[idx] + bhh[idx];
}

// ---------------- mel smooth residual block ----------------
template <typename TIN>
__global__ __launch_bounds__(256) void mel_block(const TIN* __restrict__ in,
                                                 __half* __restrict__ out,
                                                 const float* __restrict__ w,   // (3,20,3,5)
                                                 const float* __restrict__ bias) { // (3,20)
    __shared__ float xt[TT + 4][MEL];
    __shared__ float ws[900];
    __shared__ float bs[MEL];
    int bb = blockIdx.x;
    int t0 = blockIdx.y * TT;
    int tid = threadIdx.x;
    const TIN* inb = in + (size_t)bb * SS * MEL;
    for (int idx = tid; idx < (TT + 4) * MEL; idx += 256) {
        int tt = idx / MEL, ch = idx % MEL;
        int t = t0 + tt - 2;
        xt[tt][ch] = (t >= 0 && t < SS) ? (float)inb[(size_t)t * MEL + ch] : 0.f;
    }
    for (int idx = tid; idx < 900; idx += 256) ws[idx] = w[idx];
    if (tid < MEL) bs[tid] = bias[(tid % 3) * 20 + tid / 3];  // out ch 3i+j gets b[j][i]
    __syncthreads();
    for (int idx = tid; idx < TT * MEL; idx += 256) {
        int tt = idx / MEL, ch = idx % MEL;
        int i = ch / 3, j = ch % 3;
        int qb = 3 * i + (j - 1);
        float acc = bs[ch];
        #pragma unroll
        for (int c = 0; c < 3; ++c) {
            int q = qb + c;
            if (q >= 0 && q < MEL) {
                const float* wp = ws + ((j * 20 + i) * 3 + c) * 5;
                #pragma unroll
                for (int k = 0; k < 5; ++k) acc += xt[tt + k][q] * wp[k];
            }
        }
        out[(size_t)bb * SS * MEL + (size_t)(t0 + tt) * MEL + ch] =
            __float2half(acc + xt[tt + 2][ch]);
    }
}

// ---------------- multi-job input GEMM: 64 rows (one chunk) per block-row ----------------
struct GemmArgs {
    const __half* A[NL];
    const float* W[NL];
    const float* bs[NL];
    float* C[NL];
    int K[NL];
    int t0[NL];
};

__global__ __launch_bounds__(256) void gemm_pre(GemmArgs ga) {
    int j = blockIdx.z;
    int K = ga.K[j];
    const __half* Ab = ga.A[j] + ((size_t)blockIdx.x * SS + ga.t0[j]) * K;
    float* Cb = ga.C[j] + (size_t)blockIdx.x * CH * G4;
    const float* W = ga.W[j];
    const float* bsum = ga.bs[j];
    __shared__ float As[16][68];
    __shared__ float Wsh[16][68];
    int n0 = blockIdx.y * 64;
    int tid = threadIdx.x;
    int kk = tid & 15, q = tid >> 4;
    int tx = tid & 15, ty = tid >> 4;
    float acc[4][4];
    #pragma unroll
    for (int i = 0; i < 4; ++i)
        #pragma unroll
        for (int jj = 0; jj < 4; ++jj) acc[i][jj] = 0.f;

    int ktiles = (K + 15) / 16;
    for (int kt = 0; kt < ktiles; ++kt) {
        int kidx = kt * 16 + kk;
        bool kval = kidx < K;
        #pragma unroll
        for (int r = 0; r < 4; ++r)
            As[kk][q + (r << 4)] = kval ? __half2float(Ab[(size_t)(q + (r << 4)) * K + kidx]) : 0.f;
        #pragma unroll
        for (int r = 0; r < 4; ++r) {
            int g = n0 + q + (r << 4);
            Wsh[kk][q + (r << 4)] = (kval && g < G4) ? W[(size_t)g * K + kidx] : 0.f;
        }
        __syncthreads();
        #pragma unroll
        for (int k = 0; k < 16; ++k) {
            float a[4], wv[4];
            #pragma unroll
            for (int i = 0; i < 4; ++i) a[i] = As[k][ty + (i << 4)];
            #pragma unroll
            for (int jj = 0; jj < 4; ++jj) wv[jj] = Wsh[k][(tx << 2) + jj];
            #pragma unroll
            for (int i = 0; i < 4; ++i)
                #pragma unroll
                for (int jj = 0; jj < 4; ++jj) acc[i][jj] = fmaf(a[i], wv[jj], acc[i][jj]);
        }
        __syncthreads();
    }
    #pragma unroll
    for (int i = 0; i < 4; ++i) {
        #pragma unroll
        for (int jj = 0; jj < 4; ++jj) {
            int g = n0 + (tx << 2) + jj;
            if (g < G4) Cb[(size_t)(ty + (i << 4)) * G4 + g] = acc[i][jj] + bsum[g];
        }
    }
}

// ---------------- multi-job LSTM scan: weights resident in VGPRs (f16 packed) ----------------
struct ScanArgs {
    const float* pre[NL];
    const unsigned short* w4[NL];
    __half* hout[NL];
    float* hst[NL];
    float* cst[NL];
    int t0[NL];
};

// 12-wave workgroup, 1 WG/CU -> VGPR budget ~170: wreg's 96 VGPRs stay in registers.
__global__ __launch_bounds__(768, 1) void lstm_scan(ScanArgs sa) {
    int j = blockIdx.x / BB, b = blockIdx.x % BB;
    int tid = threadIdx.x;
    int t0 = sa.t0[j];
    const float* preb = sa.pre[j] + (size_t)b * CH * G4;
    const uint4* w4 = (const uint4*)sa.w4[j];
    __half* houtb = sa.hout[j] + ((size_t)b * SS + (size_t)t0) * HH;
    float* hstb = sa.hst[j] + b * HH;
    float* cstb = sa.cst[j] + b * HH;

    __shared__ __align__(16) unsigned short hs[KP];  // h state as f16
    __shared__ float gates[G4];

    // entire per-column recurrent weight slice -> 24 uint4 = 96 VGPRs, loaded once
    uint4 wreg[24];
    if (tid < G4) {
        #pragma unroll
        for (int k8 = 0; k8 < 24; ++k8) wreg[k8] = w4[k8 * G4 + tid];
    }
    float c = 0.f;
    if (tid < KP) {
        float hv = 0.f;
        if (t0 > 0 && tid < HH) { hv = hstb[tid]; c = cstb[tid]; }
        hs[tid] = __half_as_ushort(__float2half(hv));
    }
    __syncthreads();

    float pre_cur = (tid < G4) ? preb[tid] : 0.f;
    float hlast = 0.f;
    for (int t = 0; t < CH; ++t) {
        float pre_nxt = 0.f;
        if (tid < G4 && t + 1 < CH) pre_nxt = preb[(size_t)(t + 1) * G4 + tid];
        if (tid < G4) {
            float acc = pre_cur;
            const uint4* hv4 = (const uint4*)hs;
            #pragma unroll
            for (int k8 = 0; k8 < 24; ++k8) {
                uint4 h8 = hv4[k8];
                uint4 w8 = wreg[k8];
                acc = fdot2u(w8.x, h8.x, acc);
                acc = fdot2u(w8.y, h8.y, acc);
                acc = fdot2u(w8.z, h8.z, acc);
                acc = fdot2u(w8.w, h8.w, acc);
            }
            gates[tid] = acc;
        }
        __syncthreads();
        if (tid < HH) {
            float gi = gates[tid], gf = gates[HH + tid];
            float gg = gates[2 * HH + tid], go = gates[3 * HH + tid];
            float si = 1.f / (1.f + __expf(-gi));
            float sf = 1.f / (1.f + __expf(-gf));
            float so = 1.f / (1.f + __expf(-go));
            float tg = 1.f - 2.f / (__expf(2.f * gg) + 1.f);   // tanh
            c = sf * c + si * tg;
            float hn = so * (1.f - 2.f / (__expf(2.f * c) + 1.f));
            __half hh = __float2half(hn);
            hs[tid] = __half_as_ushort(hh);
            hlast = __half2float(hh);
            houtb[(size_t)t * HH + tid] = hh;
        }
        __syncthreads();
        pre_cur = pre_nxt;
    }
    if (tid < HH) { hstb[tid] = hlast; cstb[tid] = c; }
}

// ---------------- epilogue ----------------
__global__ void gather_last(const __half* __restrict__ hfin, const int* __restrict__ lens,
                            float* __restrict__ last) {
    int idx = blockIdx.x * blockDim.x + threadIdx.x;
    if (idx >= BB * HH) return;
    int b = idx / HH, d = idx % HH;
    int t = lens[b] - 1;
    t = t < 0 ? 0 : (t > SS - 1 ? SS - 1 : t);
    last[idx] = __half2float(hfin[((size_t)b * SS + t) * HH + d]);
}

// post GEMM: postb[64][8192] = leaky(last[64][180] @ post_w[8192][180]^T + pb)
// grid: 128 n-tiles of 64
__global__ __launch_bounds__(256) void post_gemm(const float* __restrict__ A,   // last (64,180)
                                                 const float* __restrict__ Bw,  // post_w (8192,180)
                                                 const float* __restrict__ pb,
                                                 float* __restrict__ Cb) {      // postb (64,8192)
    __shared__ float As[16][68];
    __shared__ float Bs[16][68];
    int n0 = blockIdx.x * 64;
    int tid = threadIdx.x;
    int kk = tid & 15, q = tid >> 4;
    int tx = tid & 15, ty = tid >> 4;
    float acc[4][4];
    #pragma unroll
    for (int i = 0; i < 4; ++i)
        #pragma unroll
        for (int jj = 0; jj < 4; ++jj) acc[i][jj] = 0.f;
    for (int kt = 0; kt < 12; ++kt) {   // 12*16 = 192 >= 180
        int kidx = kt * 16 + kk;
        bool kval = kidx < HH;
        #pragma unroll
        for (int r = 0; r < 4; ++r)
            As[kk][q + (r << 4)] = kval ? A[(size_t)(q + (r << 4)) * HH + kidx] : 0.f;
        #pragma unroll
        for (int r = 0; r < 4; ++r)
            Bs[kk][q + (r << 4)] = kval ? Bw[(size_t)(n0 + q + (r << 4)) * HH + kidx] : 0.f;
        __syncthreads();
        #pragma unroll
        for (int k = 0; k < 16; ++k) {
            float a[4], bv[4];
            #pragma unroll
            for (int i = 0; i < 4; ++i) a[i] = As[k][ty + (i << 4)];
            #pragma unroll
            for (int jj = 0; jj < 4; ++jj) bv[jj] = Bs[k][(tx << 2) + jj];
            #pragma unroll
            for (int i = 0; i < 4; ++i)
                #pragma unroll
                for (int jj = 0; jj < 4; ++jj) acc[i][jj] = fmaf(a[i], bv[jj], acc[i][jj]);
        }
        __syncthreads();
    }
    #pragma unroll
    for (int i = 0; i < 4; ++i) {
        int m = ty + (i << 4);
        #pragma unroll
        for (int jj = 0; jj < 4; ++jj) {
            int g = n0 + (tx << 2) + jj;
            float v = acc[i][jj] + pb[g];
            Cb[(size_t)m * NPOST + g] = v > 0.f ? v : 0.01f * v;
        }
    }
}

// up GEMM K-split: partial[ks][64][320] = postb[64][k0:k0+512] @ up_w[300][k0:k0+512]^T
// grid: (5 n-tiles, 16 k-splits)
__global__ __launch_bounds__(256) void up_gemm(const float* __restrict__ A,   // postb (64,8192)
                                               const float* __restrict__ Bw,  // up_w (300,8192)
                                               float* __restrict__ part) {
    __shared__ float As[16][68];
    __shared__ float Bs[16][68];
    int n0 = blockIdx.x * 64;
    int k0 = blockIdx.y * (NPOST / KSPL);
    float* Pb = part + (size_t)blockIdx.y * BB * NOUTP;
    int tid = threadIdx.x;
    int kk = tid & 15, q = tid >> 4;
    int tx = tid & 15, ty = tid >> 4;
    float acc[4][4];
    #pragma unroll
    for (int i = 0; i < 4; ++i)
        #pragma unroll
        for (int jj = 0; jj < 4; ++jj) acc[i][jj] = 0.f;
    for (int kt = 0; kt < (NPOST / KSPL) / 16; ++kt) {   // 32 tiles
        int kidx = k0 + kt * 16 + kk;
        #pragma unroll
        for (int r = 0; r < 4; ++r)
            As[kk][q + (r << 4)] = A[(size_t)(q + (r << 4)) * NPOST + kidx];
        #pragma unroll
        for (int r = 0; r < 4; ++r) {
            int g = n0 + q + (r << 4);
            Bs[kk][q + (r << 4)] = (g < NOUT) ? Bw[(size_t)g * NPOST + kidx] : 0.f;
        }
        __syncthreads();
        #pragma unroll
        for (int k = 0; k < 16; ++k) {
            float a[4], bv[4];
            #pragma unroll
            for (int i = 0; i < 4; ++i) a[i] = As[k][ty + (i << 4)];
            #pragma unroll
            for (int jj = 0; jj < 4; ++jj) bv[jj] = Bs[k][(tx << 2) + jj];
            #pragma unroll
            for (int i = 0; i < 4; ++i)
                #pragma unroll
                for (int jj = 0; jj < 4; ++jj) acc[i][jj] = fmaf(a[i], bv[jj], acc[i][jj]);
        }
        __syncthreads();
    }
    #pragma unroll
    for (int i = 0; i < 4; ++i) {
        int m = ty + (i << 4);
        #pragma unroll
        for (int jj = 0; jj < 4; ++jj) {
            int g = n0 + (tx << 2) + jj;
            Pb[(size_t)m * NOUTP + g] = acc[i][jj];
        }
    }
}

__global__ void up_reduce(const float* __restrict__ part, const float* __restrict__ ub,
                          float* __restrict__ out) {
    int idx = blockIdx.x * blockDim.x + threadIdx.x;
    if (idx >= BB * NOUT) return;
    int b = idx / NOUT, o = idx % NOUT;
    float acc = ub[o];
    #pragma unroll
    for (int ks = 0; ks < KSPL; ++ks)
        acc += part[((size_t)ks * BB + b) * NOUTP + o];
    out[(size_t)b * NOUT + o] = acc;
}

extern "C" void kernel_launch(void* const* d_in, const int* in_sizes, int n_in,
                              void* d_out, int out_size, void* d_ws, size_t ws_size,
                              hipStream_t stream) {
    const float* x        = (const float*)d_in[0];
    const int*   lens     = (const int*)d_in[1];
    const float* conv_w   = (const float*)d_in[2];
    const float* conv_b   = (const float*)d_in[3];
    const float* wih0     = (const float*)d_in[4];
    const float* wih_rest = (const float*)d_in[5];
    const float* whh      = (const float*)d_in[6];
    const float* bih      = (const float*)d_in[7];
    const float* bhh      = (const float*)d_in[8];
    const float* post_w   = (const float*)d_in[9];
    const float* post_b   = (const float*)d_in[10];
    const float* up_w     = (const float*)d_in[11];
    const float* up_b     = (const float*)d_in[12];
    float* out = (float*)d_out;
    (void)in_sizes; (void)n_in; (void)out_size;

    const size_t szMel   = (size_t)BB * SS * MEL * 2;       // 7.9 MB  (f16)
    const size_t szH     = (size_t)BB * SS * HH * 2;        // 23.6 MB (f16)
    const size_t szPre   = (size_t)BB * CH * G4 * 4;        // 11.8 MB (fp32)
    const size_t szW16   = (size_t)NL * KP * G4 * 2;        // 1.1 MB
    const size_t szBsum  = (size_t)NL * G4 * 4;
    const size_t szState = (size_t)NL * BB * HH * 4;
    const size_t szLast  = (size_t)BB * HH * 4;
    const size_t szPost  = (size_t)BB * NPOST * 4;
    const size_t szPart  = (size_t)KSPL * BB * NOUTP * 4;   // 1.3 MB
    auto pad = [](size_t v) { return (v + 255) & ~(size_t)255; };

    size_t needWF = pad(szMel) + 4 * pad(szH) + 4 * pad(szPre) + pad(szW16) +
                    pad(szBsum) + 2 * pad(szState) + pad(szLast) + pad(szPost) +
                    pad(szPart) + 4096;
    bool wavefront = ws_size >= needWF;

    char* wsp = (char*)d_ws;
    size_t off = 0;
    auto alloc = [&](size_t bytes) -> void* {
        void* p = wsp + off;
        off = (off + bytes + 255) & ~(size_t)255;
        return p;
    };

    __half* melF = (__half*)alloc(szMel);
    __half* hbuf[NL];
    if (wavefront) {
        for (int l = 0; l < NL; ++l) hbuf[l] = (__half*)alloc(szH);
    } else {
        __half* p0 = (__half*)alloc(szH);
        __half* p1 = (__half*)alloc(szH);
        hbuf[0] = p0; hbuf[1] = p1; hbuf[2] = p0; hbuf[3] = p1;
    }
    float* preC = (float*)alloc(wavefront ? 4 * pad(szPre) : szPre);
    unsigned short* w16 = (unsigned short*)alloc(szW16);
    float* bsum  = (float*)alloc(szBsum);
    float* hstates = (float*)alloc(szState);
    float* cstates = (float*)alloc(szState);
    float* lastb = (float*)alloc(szLast);
    float* postb = (float*)alloc(szPost);
    float* partb = (float*)alloc(szPart);

    prep_w16<<<(NL * KP * G4 + 255) / 256, 256, 0, stream>>>(whh, w16);
    prep_bsum<<<(NL * G4 + 255) / 256, 256, 0, stream>>>(bih, bhh, bsum);

    // 3 residual mel-smooth blocks: fp32 in -> f16 chain
    {
        __half* m0 = hbuf[0];  // scratch reuse is safe: consumed before layer0 writes
        __half* m1 = (__half*)((char*)hbuf[0] + pad(szMel));
        mel_block<float><<<dim3(BB, SS / TT), 256, 0, stream>>>(x, m0, conv_w + 0 * 900, conv_b + 0 * 60);
        mel_block<__half><<<dim3(BB, SS / TT), 256, 0, stream>>>(m0, m1, conv_w + 1 * 900, conv_b + 1 * 60);
        mel_block<__half><<<dim3(BB, SS / TT), 256, 0, stream>>>(m1, melF, conv_w + 2 * 900, conv_b + 2 * 60);
    }

    auto fillJob = [&](GemmArgs& ga, ScanArgs& sca, int nj, int l, int c, float* preBase) {
        ga.A[nj]  = (l == 0) ? melF : hbuf[l - 1];
        ga.K[nj]  = (l == 0) ? MEL : HH;
        ga.W[nj]  = (l == 0) ? wih0 : (wih_rest + (size_t)(l - 1) * G4 * HH);
        ga.bs[nj] = bsum + l * G4;
        ga.C[nj]  = preBase;
        ga.t0[nj] = c * CH;
        sca.pre[nj]  = preBase;
        sca.w4[nj]   = w16 + (size_t)l * KP * G4;
        sca.hout[nj] = hbuf[l];
        sca.hst[nj]  = hstates + (size_t)l * BB * HH;
        sca.cst[nj]  = cstates + (size_t)l * BB * HH;
        sca.t0[nj]   = c * CH;
    };

    if (wavefront) {
        for (int w = 0; w < NCH + NL - 1; ++w) {
            GemmArgs ga{}; ScanArgs sca{};
            int nj = 0;
            for (int l = 0; l < NL; ++l) {
                int c = w - l;
                if (c < 0 || c >= NCH) continue;
                float* preBase = (float*)((char*)preC + (size_t)l * pad(szPre));
                fillJob(ga, sca, nj, l, c, preBase);
                ++nj;
            }
            gemm_pre<<<dim3(BB, 12, nj), 256, 0, stream>>>(ga);
            lstm_scan<<<dim3(nj * BB), 768, 0, stream>>>(sca);
        }
    } else {
        for (int l = 0; l < NL; ++l) {
            for (int c = 0; c < NCH; ++c) {
                GemmArgs ga{}; ScanArgs sca{};
                fillJob(ga, sca, 0, l, c, preC);
                gemm_pre<<<dim3(BB, 12, 1), 256, 0, stream>>>(ga);
                lstm_scan<<<dim3(BB), 768, 0, stream>>>(sca);
            }
        }
    }

    gather_last<<<(BB * HH + 255) / 256, 256, 0, stream>>>(hbuf[NL - 1], lens, lastb);
    post_gemm<<<NPOST / 64, 256, 0, stream>>>(lastb, post_w, post_b, postb);
    up_gemm<<<dim3(NOUTP / 64, KSPL), 256, 0, stream>>>(postb, up_w, partb);
    up_reduce<<<(BB * NOUT + 255) / 256, 256, 0, stream>>>(partb, up_b, out);
}

// Round 6
// 2538.906 us; speedup vs baseline: 13.6717x; 1.2299x over previous
//
#include <hip/hip_runtime.h>
#include <hip/hip_fp16.h>

#define BB 64
#define SS 1024
#define MEL 60
#define HH 180
#define G4 720   // 4*H
#define KP 192   // padded K (h) dim for recurrent matvec: 24 blocks of 8
#define NL 4
#define NPOST 8192
#define NOUT 300
#define NOUTP 320
#define KSPL 16
#define TT 128   // mel time tile
#define CH 64    // lstm time chunk
#define NCH (SS / CH)
#define KPAIR 96 // padded f16-pair count for wih columns

#if defined(__has_builtin)
#if __has_builtin(__builtin_amdgcn_fdot2)
#define HAVE_FDOT2 1
#endif
#endif
#ifndef HAVE_FDOT2
#define HAVE_FDOT2 0
#endif

__device__ __forceinline__ float fdot2u(unsigned int w, unsigned int h, float acc) {
#if HAVE_FDOT2
    typedef _Float16 h2_t __attribute__((ext_vector_type(2)));
    union U { unsigned int u; h2_t v; };
    U a, b;
    a.u = w; b.u = h;
    return __builtin_amdgcn_fdot2(a.v, b.v, acc, false);
#else
    __half2 aw = *reinterpret_cast<const __half2*>(&w);
    __half2 ah = *reinterpret_cast<const __half2*>(&h);
    acc += __half2float(__low2half(aw)) * __half2float(__low2half(ah));
    acc += __half2float(__high2half(aw)) * __half2float(__high2half(ah));
    return acc;
#endif
}

// ---------------- prep ----------------
// w16 layout: [l][k8][g][jj] ushort = f16(whh[l][g][8*k8+jj]), zero-padded k>=180
__global__ void prep_w16(const float* __restrict__ whh, unsigned short* __restrict__ w16) {
    int idx = blockIdx.x * blockDim.x + threadIdx.x;
    int total = NL * KP * G4;
    if (idx >= total) return;
    int l = idx / (KP * G4);
    int r = idx % (KP * G4);
    int k8 = r / (G4 * 8);
    int r2 = r % (G4 * 8);
    int g = r2 / 8, jj = r2 % 8;
    int k = 8 * k8 + jj;
    float v = (k < HH) ? whh[((size_t)l * G4 + g) * HH + k] : 0.f;
    w16[idx] = __half_as_ushort(__float2half(v));
}

// wih16: [l][g][kp] uint = packed f16 pair (w[2kp], w[2kp+1]); zero beyond K
__global__ void prep_wih16(const float* __restrict__ wih0, const float* __restrict__ wih_rest,
                           unsigned int* __restrict__ w) {
    int idx = blockIdx.x * blockDim.x + threadIdx.x;
    int total = NL * G4 * KPAIR;
    if (idx >= total) return;
    int l = idx / (G4 * KPAIR);
    int r = idx % (G4 * KPAIR);
    int g = r / KPAIR, kp = r % KPAIR;
    int K = (l == 0) ? MEL : HH;
    const float* src = (l == 0) ? (wih0 + (size_t)g * MEL)
                                : (wih_rest + ((size_t)(l - 1) * G4 + g) * HH);
    float a = 0.f, b = 0.f;
    if (2 * kp < K) { a = src[2 * kp]; b = src[2 * kp + 1]; }   // K is even
    __half2 h2 = __floats2half2_rn(a, b);
    w[idx] = *(unsigned int*)&h2;
}

__global__ void prep_bsum(const float* __restrict__ bih, const float* __restrict__ bhh,
                          float* __restrict__ bsum) {
    int idx = blockIdx.x * blockDim.x + threadIdx.x;
    if (idx >= NL * G4) return;
    bsum[idx] = bih[idx] + bhh[idx];
}

// ---------------- mel smooth residual block ----------------
template <typename TIN>
__global__ __launch_bounds__(256) void mel_block(const TIN* __restrict__ in,
                                                 __half* __restrict__ out,
                                                 const float* __restrict__ w,   // (3,20,3,5)
                                                 const float* __restrict__ bias) { // (3,20)
    __shared__ float xt[TT + 4][MEL];
    __shared__ float ws[900];
    __shared__ float bs[MEL];
    int bb = blockIdx.x;
    int t0 = blockIdx.y * TT;
    int tid = threadIdx.x;
    const TIN* inb = in + (size_t)bb * SS * MEL;
    for (int idx = tid; idx < (TT + 4) * MEL; idx += 256) {
        int tt = idx / MEL, ch = idx % MEL;
        int t = t0 + tt - 2;
        xt[tt][ch] = (t >= 0 && t < SS) ? (float)inb[(size_t)t * MEL + ch] : 0.f;
    }
    for (int idx = tid; idx < 900; idx += 256) ws[idx] = w[idx];
    if (tid < MEL) bs[tid] = bias[(tid % 3) * 20 + tid / 3];  // out ch 3i+j gets b[j][i]
    __syncthreads();
    for (int idx = tid; idx < TT * MEL; idx += 256) {
        int tt = idx / MEL, ch = idx % MEL;
        int i = ch / 3, j = ch % 3;
        int qb = 3 * i + (j - 1);
        float acc = bs[ch];
        #pragma unroll
        for (int c = 0; c < 3; ++c) {
            int q = qb + c;
            if (q >= 0 && q < MEL) {
                const float* wp = ws + ((j * 20 + i) * 3 + c) * 5;
                #pragma unroll
                for (int k = 0; k < 5; ++k) acc += xt[tt + k][q] * wp[k];
            }
        }
        out[(size_t)bb * SS * MEL + (size_t)(t0 + tt) * MEL + ch] =
            __float2half(acc + xt[tt + 2][ch]);
    }
}

// ---------------- f16 input GEMM (multi-job): C[m][g] = A[m][:] . Wg + bsum ----------------
struct GemmArgs {
    const __half* A[16];
    const unsigned int* W[16];
    const float* bs[16];
    __half* C[16];
    size_t cbs[16];   // C batch stride (elements)
    int K[16];
    int KT[16];       // k-pair tiles of 8
    int t0[16];
};

__global__ __launch_bounds__(256) void gemm_pre(GemmArgs ga) {
    int j = blockIdx.z;
    int K = ga.K[j], KT = ga.KT[j];
    const __half* Ab = ga.A[j] + ((size_t)blockIdx.x * SS + ga.t0[j]) * K;
    __half* Cb = ga.C[j] + (size_t)blockIdx.x * ga.cbs[j];
    const unsigned int* Wj = ga.W[j];
    const float* bsum = ga.bs[j];
    __shared__ unsigned int A16[8][72];
    __shared__ unsigned int W16[8][72];
    int n0 = blockIdx.y * 64;
    int tid = threadIdx.x;
    int tx = tid & 15, ty = tid >> 4;
    int kpl = tid & 7, mg = tid >> 3;   // stage role: mg 0..31
    float acc[4][4];
    #pragma unroll
    for (int i = 0; i < 4; ++i)
        #pragma unroll
        for (int jn = 0; jn < 4; ++jn) acc[i][jn] = 0.f;

    for (int kt = 0; kt < KT; ++kt) {
        int kp = kt * 8 + kpl;
        #pragma unroll
        for (int r = 0; r < 2; ++r) {
            int m = mg + 32 * r;
            unsigned int av = 0u;
            if (2 * kp < K) av = *(const unsigned int*)(Ab + (size_t)m * K + 2 * kp);
            A16[kpl][m] = av;
            int g = n0 + m;
            W16[kpl][m] = (g < G4) ? Wj[(size_t)g * KPAIR + kp] : 0u;
        }
        __syncthreads();
        #pragma unroll
        for (int k = 0; k < 8; ++k) {
            unsigned int a[4], b[4];
            #pragma unroll
            for (int i = 0; i < 4; ++i) a[i] = A16[k][ty + (i << 4)];
            #pragma unroll
            for (int jn = 0; jn < 4; ++jn) b[jn] = W16[k][(tx << 2) + jn];
            #pragma unroll
            for (int i = 0; i < 4; ++i)
                #pragma unroll
                for (int jn = 0; jn < 4; ++jn) acc[i][jn] = fdot2u(b[jn], a[i], acc[i][jn]);
        }
        __syncthreads();
    }
    int g0 = n0 + (tx << 2);
    if (g0 < G4) {
        #pragma unroll
        for (int i = 0; i < 4; ++i) {
            int m = ty + (i << 4);
            __half2 p0 = __floats2half2_rn(acc[i][0] + bsum[g0], acc[i][1] + bsum[g0 + 1]);
            __half2 p1 = __floats2half2_rn(acc[i][2] + bsum[g0 + 2], acc[i][3] + bsum[g0 + 3]);
            *(__half2*)(Cb + (size_t)m * G4 + g0) = p0;
            *(__half2*)(Cb + (size_t)m * G4 + g0 + 2) = p1;
        }
    }
}

// ---------------- LSTM scan: weights pinned in VGPRs ----------------
struct ScanArgs {
    const __half* pre[NL];
    size_t pbs[NL];          // pre batch stride (elements)
    const unsigned short* w4[NL];
    __half* hout[NL];
    float* hst[NL];
    float* cst[NL];
    int t0[NL];
};

__global__ __launch_bounds__(768) __attribute__((amdgpu_waves_per_eu(3, 3)))
void lstm_scan(ScanArgs sa) {
    int j = blockIdx.x / BB, b = blockIdx.x % BB;
    int tid = threadIdx.x;
    int t0 = sa.t0[j];
    const __half* preb = sa.pre[j] + (size_t)b * sa.pbs[j];
    const uint4* w4 = (const uint4*)sa.w4[j];
    __half* houtb = sa.hout[j] + ((size_t)b * SS + (size_t)t0) * HH;
    float* hstb = sa.hst[j] + b * HH;
    float* cstb = sa.cst[j] + b * HH;

    __shared__ __align__(16) unsigned short hs[KP];  // h state as f16
    __shared__ float gates[G4];

    // full per-column recurrent weight slice: 24 uint4 = 96 VGPRs, loaded once,
    // pinned via opaque asm so the compiler cannot re-load them per step.
    uint4 wreg[24];
    if (tid < G4) {
        #pragma unroll
        for (int k8 = 0; k8 < 24; ++k8) wreg[k8] = w4[k8 * G4 + tid];
    }
    #pragma unroll
    for (int k8 = 0; k8 < 24; ++k8)
        asm volatile("" : "+v"(wreg[k8].x), "+v"(wreg[k8].y), "+v"(wreg[k8].z), "+v"(wreg[k8].w));

    float c = 0.f;
    if (tid < KP) {
        float hv = 0.f;
        if (t0 > 0 && tid < HH) { hv = hstb[tid]; c = cstb[tid]; }
        hs[tid] = __half_as_ushort(__float2half(hv));
    }
    __syncthreads();

    float pre_cur = (tid < G4) ? __half2float(preb[tid]) : 0.f;
    float hlast = 0.f;
    for (int t = 0; t < CH; ++t) {
        float pre_nxt = 0.f;
        if (tid < G4 && t + 1 < CH) pre_nxt = __half2float(preb[(size_t)(t + 1) * G4 + tid]);
        if (tid < G4) {
            float acc = pre_cur;
            const uint4* hv4 = (const uint4*)hs;
            #pragma unroll
            for (int k8 = 0; k8 < 24; ++k8) {
                uint4 h8 = hv4[k8];
                uint4 w8 = wreg[k8];
                acc = fdot2u(w8.x, h8.x, acc);
                acc = fdot2u(w8.y, h8.y, acc);
                acc = fdot2u(w8.z, h8.z, acc);
                acc = fdot2u(w8.w, h8.w, acc);
            }
            gates[tid] = acc;
        }
        __syncthreads();
        if (tid < HH) {
            float gi = gates[tid], gf = gates[HH + tid];
            float gg = gates[2 * HH + tid], go = gates[3 * HH + tid];
            float si = 1.f / (1.f + __expf(-gi));
            float sf = 1.f / (1.f + __expf(-gf));
            float so = 1.f / (1.f + __expf(-go));
            float tg = 1.f - 2.f / (__expf(2.f * gg) + 1.f);   // tanh
            c = sf * c + si * tg;
            float hn = so * (1.f - 2.f / (__expf(2.f * c) + 1.f));
            __half hh = __float2half(hn);
            hs[tid] = __half_as_ushort(hh);
            hlast = __half2float(hh);
            houtb[(size_t)t * HH + tid] = hh;
        }
        __syncthreads();
        pre_cur = pre_nxt;
    }
    if (tid < HH) { hstb[tid] = hlast; cstb[tid] = c; }
}

// ---------------- epilogue ----------------
__global__ void gather_last(const __half* __restrict__ hfin, const int* __restrict__ lens,
                            float* __restrict__ last) {
    int idx = blockIdx.x * blockDim.x + threadIdx.x;
    if (idx >= BB * HH) return;
    int b = idx / HH, d = idx % HH;
    int t = lens[b] - 1;
    t = t < 0 ? 0 : (t > SS - 1 ? SS - 1 : t);
    last[idx] = __half2float(hfin[((size_t)b * SS + t) * HH + d]);
}

__global__ __launch_bounds__(256) void post_gemm(const float* __restrict__ A,   // last (64,180)
                                                 const float* __restrict__ Bw,  // post_w (8192,180)
                                                 const float* __restrict__ pb,
                                                 float* __restrict__ Cb) {      // postb (64,8192)
    __shared__ float As[16][68];
    __shared__ float Bs[16][68];
    int n0 = blockIdx.x * 64;
    int tid = threadIdx.x;
    int kk = tid & 15, q = tid >> 4;
    int tx = tid & 15, ty = tid >> 4;
    float acc[4][4];
    #pragma unroll
    for (int i = 0; i < 4; ++i)
        #pragma unroll
        for (int jj = 0; jj < 4; ++jj) acc[i][jj] = 0.f;
    for (int kt = 0; kt < 12; ++kt) {
        int kidx = kt * 16 + kk;
        bool kval = kidx < HH;
        #pragma unroll
        for (int r = 0; r < 4; ++r)
            As[kk][q + (r << 4)] = kval ? A[(size_t)(q + (r << 4)) * HH + kidx] : 0.f;
        #pragma unroll
        for (int r = 0; r < 4; ++r)
            Bs[kk][q + (r << 4)] = kval ? Bw[(size_t)(n0 + q + (r << 4)) * HH + kidx] : 0.f;
        __syncthreads();
        #pragma unroll
        for (int k = 0; k < 16; ++k) {
            float a[4], bv[4];
            #pragma unroll
            for (int i = 0; i < 4; ++i) a[i] = As[k][ty + (i << 4)];
            #pragma unroll
            for (int jj = 0; jj < 4; ++jj) bv[jj] = Bs[k][(tx << 2) + jj];
            #pragma unroll
            for (int i = 0; i < 4; ++i)
                #pragma unroll
                for (int jj = 0; jj < 4; ++jj) acc[i][jj] = fmaf(a[i], bv[jj], acc[i][jj]);
        }
        __syncthreads();
    }
    #pragma unroll
    for (int i = 0; i < 4; ++i) {
        int m = ty + (i << 4);
        #pragma unroll
        for (int jj = 0; jj < 4; ++jj) {
            int g = n0 + (tx << 2) + jj;
            float v = acc[i][jj] + pb[g];
            Cb[(size_t)m * NPOST + g] = v > 0.f ? v : 0.01f * v;
        }
    }
}

__global__ __launch_bounds__(256) void up_gemm(const float* __restrict__ A,   // postb (64,8192)
                                               const float* __restrict__ Bw,  // up_w (300,8192)
                                               float* __restrict__ part) {
    __shared__ float As[16][68];
    __shared__ float Bs[16][68];
    int n0 = blockIdx.x * 64;
    int k0 = blockIdx.y * (NPOST / KSPL);
    float* Pb = part + (size_t)blockIdx.y * BB * NOUTP;
    int tid = threadIdx.x;
    int kk = tid & 15, q = tid >> 4;
    int tx = tid & 15, ty = tid >> 4;
    float acc[4][4];
    #pragma unroll
    for (int i = 0; i < 4; ++i)
        #pragma unroll
        for (int jj = 0; jj < 4; ++jj) acc[i][jj] = 0.f;
    for (int kt = 0; kt < (NPOST / KSPL) / 16; ++kt) {
        int kidx = k0 + kt * 16 + kk;
        #pragma unroll
        for (int r = 0; r < 4; ++r)
            As[kk][q + (r << 4)] = A[(size_t)(q + (r << 4)) * NPOST + kidx];
        #pragma unroll
        for (int r = 0; r < 4; ++r) {
            int g = n0 + q + (r << 4);
            Bs[kk][q + (r << 4)] = (g < NOUT) ? Bw[(size_t)g * NPOST + kidx] : 0.f;
        }
        __syncthreads();
        #pragma unroll
        for (int k = 0; k < 16; ++k) {
            float a[4], bv[4];
            #pragma unroll
            for (int i = 0; i < 4; ++i) a[i] = As[k][ty + (i << 4)];
            #pragma unroll
            for (int jj = 0; jj < 4; ++jj) bv[jj] = Bs[k][(tx << 2) + jj];
            #pragma unroll
            for (int i = 0; i < 4; ++i)
                #pragma unroll
                for (int jj = 0; jj < 4; ++jj) acc[i][jj] = fmaf(a[i], bv[jj], acc[i][jj]);
        }
        __syncthreads();
    }
    #pragma unroll
    for (int i = 0; i < 4; ++i) {
        int m = ty + (i << 4);
        #pragma unroll
        for (int jj = 0; jj < 4; ++jj) {
            int g = n0 + (tx << 2) + jj;
            Pb[(size_t)m * NOUTP + g] = acc[i][jj];
        }
    }
}

__global__ void up_reduce(const float* __restrict__ part, const float* __restrict__ ub,
                          float* __restrict__ out) {
    int idx = blockIdx.x * blockDim.x + threadIdx.x;
    if (idx >= BB * NOUT) return;
    int b = idx / NOUT, o = idx % NOUT;
    float acc = ub[o];
    #pragma unroll
    for (int ks = 0; ks < KSPL; ++ks)
        acc += part[((size_t)ks * BB + b) * NOUTP + o];
    out[(size_t)b * NOUT + o] = acc;
}

extern "C" void kernel_launch(void* const* d_in, const int* in_sizes, int n_in,
                              void* d_out, int out_size, void* d_ws, size_t ws_size,
                              hipStream_t stream) {
    const float* x        = (const float*)d_in[0];
    const int*   lens     = (const int*)d_in[1];
    const float* conv_w   = (const float*)d_in[2];
    const float* conv_b   = (const float*)d_in[3];
    const float* wih0     = (const float*)d_in[4];
    const float* wih_rest = (const float*)d_in[5];
    const float* whh      = (const float*)d_in[6];
    const float* bih      = (const float*)d_in[7];
    const float* bhh      = (const float*)d_in[8];
    const float* post_w   = (const float*)d_in[9];
    const float* post_b   = (const float*)d_in[10];
    const float* up_w     = (const float*)d_in[11];
    const float* up_b     = (const float*)d_in[12];
    float* out = (float*)d_out;
    (void)in_sizes; (void)n_in; (void)out_size;

    auto pad = [](size_t v) { return (v + 255) & ~(size_t)255; };
    const size_t szMel   = (size_t)BB * SS * MEL * 2;       // 7.9 MB  f16
    const size_t szH     = (size_t)BB * SS * HH * 2;        // 23.6 MB f16
    const size_t szPre0  = (size_t)BB * SS * G4 * 2;        // 94.4 MB f16 (full layer-0 pre)
    const size_t szSlot  = (size_t)BB * CH * G4 * 2;        // 5.9 MB  f16
    const size_t szW16   = (size_t)NL * KP * G4 * 2;
    const size_t szWih   = (size_t)NL * G4 * KPAIR * 4;
    const size_t szBsum  = (size_t)NL * G4 * 4;
    const size_t szState = (size_t)NL * BB * HH * 4;
    const size_t szLast  = (size_t)BB * HH * 4;
    const size_t szPost  = (size_t)BB * NPOST * 4;
    const size_t szPart  = (size_t)KSPL * BB * NOUTP * 4;

    size_t commonSmall = pad(szW16) + pad(szWih) + pad(szBsum) + 2 * pad(szState) +
                         pad(szLast) + pad(szPost) + pad(szPart) + 4096;
    size_t need1 = pad(szMel) + 4 * pad(szH) + pad(szPre0) + 3 * pad(szSlot) + commonSmall;
    size_t need2 = pad(szMel) + 4 * pad(szH) + 4 * pad(szSlot) + commonSmall;
    int tier = (ws_size >= need1) ? 1 : ((ws_size >= need2) ? 2 : 3);

    char* wsp = (char*)d_ws;
    size_t off = 0;
    auto alloc = [&](size_t bytes) -> void* {
        void* p = wsp + off;
        off = (off + bytes + 255) & ~(size_t)255;
        return p;
    };

    __half* melF = (__half*)alloc(szMel);
    __half* hbuf[NL];
    if (tier <= 2) {
        for (int l = 0; l < NL; ++l) hbuf[l] = (__half*)alloc(szH);
    } else {
        __half* p0 = (__half*)alloc(szH);
        __half* p1 = (__half*)alloc(szH);
        hbuf[0] = p0; hbuf[1] = p1; hbuf[2] = p0; hbuf[3] = p1;
    }
    __half* pre0 = nullptr;
    __half* slot[NL] = {nullptr, nullptr, nullptr, nullptr};
    if (tier == 1) {
        pre0 = (__half*)alloc(szPre0);
        for (int l = 1; l < NL; ++l) slot[l] = (__half*)alloc(szSlot);
    } else if (tier == 2) {
        for (int l = 0; l < NL; ++l) slot[l] = (__half*)alloc(szSlot);
    } else {
        slot[0] = (__half*)alloc(szSlot);
        for (int l = 1; l < NL; ++l) slot[l] = slot[0];
    }
    unsigned short* w16 = (unsigned short*)alloc(szW16);
    unsigned int* wih16 = (unsigned int*)alloc(szWih);
    float* bsum  = (float*)alloc(szBsum);
    float* hstates = (float*)alloc(szState);
    float* cstates = (float*)alloc(szState);
    float* lastb = (float*)alloc(szLast);
    float* postb = (float*)alloc(szPost);
    float* partb = (float*)alloc(szPart);

    prep_w16<<<(NL * KP * G4 + 255) / 256, 256, 0, stream>>>(whh, w16);
    prep_wih16<<<(NL * G4 * KPAIR + 255) / 256, 256, 0, stream>>>(wih0, wih_rest, wih16);
    prep_bsum<<<(NL * G4 + 255) / 256, 256, 0, stream>>>(bih, bhh, bsum);

    // mel blocks (scratch inside hbuf[0], consumed before layer-0 scan writes it)
    {
        __half* m0 = hbuf[0];
        __half* m1 = (__half*)((char*)hbuf[0] + pad(szMel));
        mel_block<float><<<dim3(BB, SS / TT), 256, 0, stream>>>(x, m0, conv_w + 0 * 900, conv_b + 0 * 60);
        mel_block<__half><<<dim3(BB, SS / TT), 256, 0, stream>>>(m0, m1, conv_w + 1 * 900, conv_b + 1 * 60);
        mel_block<__half><<<dim3(BB, SS / TT), 256, 0, stream>>>(m1, melF, conv_w + 2 * 900, conv_b + 2 * 60);
    }

    auto setGemmJob = [&](GemmArgs& ga, int nj, int l, int c) {
        ga.A[nj]  = (l == 0) ? melF : hbuf[l - 1];
        ga.K[nj]  = (l == 0) ? MEL : HH;
        ga.KT[nj] = (l == 0) ? 4 : 12;
        ga.W[nj]  = wih16 + (size_t)l * G4 * KPAIR;
        ga.bs[nj] = bsum + l * G4;
        if (tier == 1 && l == 0) {
            ga.C[nj] = pre0 + (size_t)c * CH * G4;
            ga.cbs[nj] = (size_t)SS * G4;
        } else {
            ga.C[nj] = slot[l];
            ga.cbs[nj] = (size_t)CH * G4;
        }
        ga.t0[nj] = c * CH;
    };
    auto setScanJob = [&](ScanArgs& sa, int nj, int l, int c) {
        if (tier == 1 && l == 0) {
            sa.pre[nj] = pre0 + (size_t)c * CH * G4;
            sa.pbs[nj] = (size_t)SS * G4;
        } else {
            sa.pre[nj] = slot[l];
            sa.pbs[nj] = (size_t)CH * G4;
        }
        sa.w4[nj]   = w16 + (size_t)l * KP * G4;
        sa.hout[nj] = hbuf[l];
        sa.hst[nj]  = hstates + (size_t)l * BB * HH;
        sa.cst[nj]  = cstates + (size_t)l * BB * HH;
        sa.t0[nj]   = c * CH;
    };

    if (tier <= 2) {
        if (tier == 1) {
            // entire layer-0 pre in one dispatch
            GemmArgs ga{};
            for (int c = 0; c < NCH; ++c) setGemmJob(ga, c, 0, c);
            gemm_pre<<<dim3(BB, 12, NCH), 256, 0, stream>>>(ga);
        }
        int lmin = (tier == 1) ? 1 : 0;
        for (int w = 0; w < NCH + NL - 1; ++w) {
            GemmArgs ga{};
            int njg = 0;
            for (int l = lmin; l < NL; ++l) {
                int c = w - l;
                if (c < 0 || c >= NCH) continue;
                setGemmJob(ga, njg++, l, c);
            }
            if (njg) gemm_pre<<<dim3(BB, 12, njg), 256, 0, stream>>>(ga);
            ScanArgs sa{};
            int njs = 0;
            for (int l = 0; l < NL; ++l) {
                int c = w - l;
                if (c < 0 || c >= NCH) continue;
                setScanJob(sa, njs++, l, c);
            }
            if (njs) lstm_scan<<<dim3(njs * BB), 768, 0, stream>>>(sa);
        }
    } else {
        for (int l = 0; l < NL; ++l) {
            for (int c = 0; c < NCH; ++c) {
                GemmArgs ga{}; ScanArgs sa{};
                setGemmJob(ga, 0, l, c);
                gemm_pre<<<dim3(BB, 12, 1), 256, 0, stream>>>(ga);
                setScanJob(sa, 0, l, c);
                lstm_scan<<<dim3(BB), 768, 0, stream>>>(sa);
            }
        }
    }

    gather_last<<<(BB * HH + 255) / 256, 256, 0, stream>>>(hbuf[NL - 1], lens, lastb);
    post_gemm<<<NPOST / 64, 256, 0, stream>>>(lastb, post_w, post_b, postb);
    up_gemm<<<dim3(NOUTP / 64, KSPL), 256, 0, stream>>>(postb, up_w, partb);
    up_reduce<<<(BB * NOUT + 255) / 256, 256, 0, stream>>>(partb, up_b, out);
}

// Round 7
// 2183.413 us; speedup vs baseline: 15.8977x; 1.1628x over previous
//
#include <hip/hip_runtime.h>
#include <hip/hip_fp16.h>

#define BB 64
#define SS 1024
#define MEL 60
#define HH 180
#define G4 720   // 4*H
#define G4P 768  // padded column count (48 groups of 16)
#define NCG 48   // column groups
#define NKS 6    // k-steps of 32 (KP=192)
#define KP 192
#define NL 4
#define NPOST 8192
#define NOUT 300
#define NOUTP 320
#define KSPL 16
#define TT 128
#define CH 64
#define NCH (SS / CH)
#define KPAIR 96

typedef _Float16 f16x8 __attribute__((ext_vector_type(8)));
typedef float f32x4 __attribute__((ext_vector_type(4)));

#if defined(__has_builtin)
#if __has_builtin(__builtin_amdgcn_fdot2)
#define HAVE_FDOT2 1
#endif
#endif
#ifndef HAVE_FDOT2
#define HAVE_FDOT2 0
#endif

__device__ __forceinline__ float fdot2u(unsigned int w, unsigned int h, float acc) {
#if HAVE_FDOT2
    typedef _Float16 h2_t __attribute__((ext_vector_type(2)));
    union U { unsigned int u; h2_t v; };
    U a, b;
    a.u = w; b.u = h;
    return __builtin_amdgcn_fdot2(a.v, b.v, acc, false);
#else
    __half2 aw = *reinterpret_cast<const __half2*>(&w);
    __half2 ah = *reinterpret_cast<const __half2*>(&h);
    acc += __half2float(__low2half(aw)) * __half2float(__low2half(ah));
    acc += __half2float(__high2half(aw)) * __half2float(__high2half(ah));
    return acc;
#endif
}

union WU { uint4 u; f16x8 f; };

// ---------------- prep ----------------
// MFMA weight fragments: wmf[l][cg][ks][lane] = uint4 of 8 f16:
//   W[k = ks*32 + (lane>>4)*8 + j][col = cg*16 + (lane&15)], zero-padded.
__global__ void prep_wmf(const float* __restrict__ whh, uint4* __restrict__ wmf) {
    int idx = blockIdx.x * blockDim.x + threadIdx.x;
    int total = NL * NCG * NKS * 64;
    if (idx >= total) return;
    int l = idx / (NCG * NKS * 64);
    int r = idx % (NCG * NKS * 64);
    int cg = r / (NKS * 64);
    int r2 = r % (NKS * 64);
    int ks = r2 / 64, lane = r2 % 64;
    int col = cg * 16 + (lane & 15);
    unsigned short v[8];
    #pragma unroll
    for (int j = 0; j < 8; ++j) {
        int k = ks * 32 + ((lane >> 4) << 3) + j;
        float f = (k < HH && col < G4) ? whh[((size_t)l * G4 + col) * HH + k] : 0.f;
        v[j] = __half_as_ushort(__float2half(f));
    }
    uint4 u;
    u.x = (unsigned)v[0] | ((unsigned)v[1] << 16);
    u.y = (unsigned)v[2] | ((unsigned)v[3] << 16);
    u.z = (unsigned)v[4] | ((unsigned)v[5] << 16);
    u.w = (unsigned)v[6] | ((unsigned)v[7] << 16);
    wmf[idx] = u;
}

// wih16: [l][g][kp] uint = packed f16 pair; zero beyond K
__global__ void prep_wih16(const float* __restrict__ wih0, const float* __restrict__ wih_rest,
                           unsigned int* __restrict__ w) {
    int idx = blockIdx.x * blockDim.x + threadIdx.x;
    int total = NL * G4 * KPAIR;
    if (idx >= total) return;
    int l = idx / (G4 * KPAIR);
    int r = idx % (G4 * KPAIR);
    int g = r / KPAIR, kp = r % KPAIR;
    int K = (l == 0) ? MEL : HH;
    const float* src = (l == 0) ? (wih0 + (size_t)g * MEL)
                                : (wih_rest + ((size_t)(l - 1) * G4 + g) * HH);
    float a = 0.f, b = 0.f;
    if (2 * kp < K) { a = src[2 * kp]; b = src[2 * kp + 1]; }
    __half2 h2 = __floats2half2_rn(a, b);
    w[idx] = *(unsigned int*)&h2;
}

__global__ void prep_bsum(const float* __restrict__ bih, const float* __restrict__ bhh,
                          float* __restrict__ bsum) {
    int idx = blockIdx.x * blockDim.x + threadIdx.x;
    if (idx >= NL * G4) return;
    bsum[idx] = bih[idx] + bhh[idx];
}

// ---------------- mel smooth residual block ----------------
template <typename TIN>
__global__ __launch_bounds__(256) void mel_block(const TIN* __restrict__ in,
                                                 __half* __restrict__ out,
                                                 const float* __restrict__ w,
                                                 const float* __restrict__ bias) {
    __shared__ float xt[TT + 4][MEL];
    __shared__ float ws[900];
    __shared__ float bs[MEL];
    int bb = blockIdx.x;
    int t0 = blockIdx.y * TT;
    int tid = threadIdx.x;
    const TIN* inb = in + (size_t)bb * SS * MEL;
    for (int idx = tid; idx < (TT + 4) * MEL; idx += 256) {
        int tt = idx / MEL, ch = idx % MEL;
        int t = t0 + tt - 2;
        xt[tt][ch] = (t >= 0 && t < SS) ? (float)inb[(size_t)t * MEL + ch] : 0.f;
    }
    for (int idx = tid; idx < 900; idx += 256) ws[idx] = w[idx];
    if (tid < MEL) bs[tid] = bias[(tid % 3) * 20 + tid / 3];
    __syncthreads();
    for (int idx = tid; idx < TT * MEL; idx += 256) {
        int tt = idx / MEL, ch = idx % MEL;
        int i = ch / 3, j = ch % 3;
        int qb = 3 * i + (j - 1);
        float acc = bs[ch];
        #pragma unroll
        for (int c = 0; c < 3; ++c) {
            int q = qb + c;
            if (q >= 0 && q < MEL) {
                const float* wp = ws + ((j * 20 + i) * 3 + c) * 5;
                #pragma unroll
                for (int k = 0; k < 5; ++k) acc += xt[tt + k][q] * wp[k];
            }
        }
        out[(size_t)bb * SS * MEL + (size_t)(t0 + tt) * MEL + ch] =
            __float2half(acc + xt[tt + 2][ch]);
    }
}

// ---------------- f16 input GEMM (multi-job) ----------------
struct GemmArgs {
    const __half* A[16];
    const unsigned int* W[16];
    const float* bs[16];
    __half* C[16];
    size_t cbs[16];
    int K[16];
    int KT[16];
    int t0[16];
};

__global__ __launch_bounds__(256) void gemm_pre(GemmArgs ga) {
    int j = blockIdx.z;
    int K = ga.K[j], KT = ga.KT[j];
    const __half* Ab = ga.A[j] + ((size_t)blockIdx.x * SS + ga.t0[j]) * K;
    __half* Cb = ga.C[j] + (size_t)blockIdx.x * ga.cbs[j];
    const unsigned int* Wj = ga.W[j];
    const float* bsum = ga.bs[j];
    __shared__ unsigned int A16[8][72];
    __shared__ unsigned int W16[8][72];
    int n0 = blockIdx.y * 64;
    int tid = threadIdx.x;
    int tx = tid & 15, ty = tid >> 4;
    int kpl = tid & 7, mg = tid >> 3;
    float acc[4][4];
    #pragma unroll
    for (int i = 0; i < 4; ++i)
        #pragma unroll
        for (int jn = 0; jn < 4; ++jn) acc[i][jn] = 0.f;

    for (int kt = 0; kt < KT; ++kt) {
        int kp = kt * 8 + kpl;
        #pragma unroll
        for (int r = 0; r < 2; ++r) {
            int m = mg + 32 * r;
            unsigned int av = 0u;
            if (2 * kp < K) av = *(const unsigned int*)(Ab + (size_t)m * K + 2 * kp);
            A16[kpl][m] = av;
            int g = n0 + m;
            W16[kpl][m] = (g < G4) ? Wj[(size_t)g * KPAIR + kp] : 0u;
        }
        __syncthreads();
        #pragma unroll
        for (int k = 0; k < 8; ++k) {
            unsigned int a[4], b[4];
            #pragma unroll
            for (int i = 0; i < 4; ++i) a[i] = A16[k][ty + (i << 4)];
            #pragma unroll
            for (int jn = 0; jn < 4; ++jn) b[jn] = W16[k][(tx << 2) + jn];
            #pragma unroll
            for (int i = 0; i < 4; ++i)
                #pragma unroll
                for (int jn = 0; jn < 4; ++jn) acc[i][jn] = fdot2u(b[jn], a[i], acc[i][jn]);
        }
        __syncthreads();
    }
    int g0 = n0 + (tx << 2);
    if (g0 < G4) {
        #pragma unroll
        for (int i = 0; i < 4; ++i) {
            int m = ty + (i << 4);
            __half2 p0 = __floats2half2_rn(acc[i][0] + bsum[g0], acc[i][1] + bsum[g0 + 1]);
            __half2 p1 = __floats2half2_rn(acc[i][2] + bsum[g0 + 2], acc[i][3] + bsum[g0 + 3]);
            *(__half2*)(Cb + (size_t)m * G4 + g0) = p0;
            *(__half2*)(Cb + (size_t)m * G4 + g0 + 2) = p1;
        }
    }
}

// ---------------- LSTM scan: MFMA recurrent matvec, weights in AGPR/VGPR fragments ----------------
struct ScanArgs {
    const __half* pre[NL];
    size_t pbs[NL];
    const uint4* wmf[NL];
    __half* hout[NL];
    float* hst[NL];
    float* cst[NL];
    int t0[NL];
};

__global__ __launch_bounds__(768) __attribute__((amdgpu_waves_per_eu(3, 3)))
void lstm_scan(ScanArgs sa) {
    int j = blockIdx.x / BB, b = blockIdx.x % BB;
    int tid = threadIdx.x;
    int wv = tid >> 6, lane = tid & 63;
    int t0 = sa.t0[j];
    const __half* preb = sa.pre[j] + (size_t)b * sa.pbs[j];
    const uint4* wmf = sa.wmf[j];
    __half* houtb = sa.hout[j] + ((size_t)b * SS + (size_t)t0) * HH;
    float* hstb = sa.hst[j] + b * HH;
    float* cstb = sa.cst[j] + b * HH;

    __shared__ __align__(16) unsigned short hs[KP];  // h state, f16
    __shared__ float gates[G4P];

    // 24 weight fragments per thread (4 col-groups x 6 k-steps), loaded once per chunk.
    // MFMA reads them directly from VGPR/AGPR - no per-step moves.
    uint4 wfr[24];
    #pragma unroll
    for (int q = 0; q < 4; ++q)
        #pragma unroll
        for (int ks = 0; ks < NKS; ++ks)
            wfr[q * NKS + ks] = wmf[(((size_t)(wv * 4 + q)) * NKS + ks) * 64 + lane];
    #pragma unroll
    for (int r = 0; r < 24; ++r)
        asm volatile("" : "+v"(wfr[r].x), "+v"(wfr[r].y), "+v"(wfr[r].z), "+v"(wfr[r].w));

    float c = 0.f, hlast = 0.f;
    if (tid < KP) {
        float hv = 0.f;
        if (t0 > 0 && tid < HH) { hv = hstb[tid]; c = cstb[tid]; }
        hs[tid] = __half_as_ushort(__float2half(hv));
    }
    __syncthreads();

    // pre prefetch (nonlin threads)
    float pc0 = 0.f, pc1 = 0.f, pc2 = 0.f, pc3 = 0.f;
    if (tid < HH) {
        pc0 = __half2float(preb[tid]);
        pc1 = __half2float(preb[HH + tid]);
        pc2 = __half2float(preb[2 * HH + tid]);
        pc3 = __half2float(preb[3 * HH + tid]);
    }

    int hoff = (lane >> 4) << 4;  // byte offset of this lane-group's 8 f16 within a k-step
    for (int t = 0; t < CH; ++t) {
        // prefetch next step's pre (latency hidden under mfma phase)
        float pn0 = 0.f, pn1 = 0.f, pn2 = 0.f, pn3 = 0.f;
        if (tid < HH && t + 1 < CH) {
            const __half* pp = preb + (size_t)(t + 1) * G4 + tid;
            pn0 = __half2float(pp[0]);
            pn1 = __half2float(pp[HH]);
            pn2 = __half2float(pp[2 * HH]);
            pn3 = __half2float(pp[3 * HH]);
        }
        // mfma phase: gates[cg*16+n] = sum_k h[k] * W[k][cg*16+n]
        f16x8 hf[NKS];
        #pragma unroll
        for (int ks = 0; ks < NKS; ++ks) {
            WU hu;
            hu.u = *(const uint4*)((const char*)hs + ks * 64 + hoff);
            hf[ks] = hu.f;
        }
        f32x4 acc0 = {0.f, 0.f, 0.f, 0.f}, acc1 = acc0, acc2 = acc0, acc3 = acc0;
        #pragma unroll
        for (int ks = 0; ks < NKS; ++ks) {
            WU w0, w1, w2, w3;
            w0.u = wfr[0 * NKS + ks]; w1.u = wfr[1 * NKS + ks];
            w2.u = wfr[2 * NKS + ks]; w3.u = wfr[3 * NKS + ks];
            acc0 = __builtin_amdgcn_mfma_f32_16x16x32_f16(hf[ks], w0.f, acc0, 0, 0, 0);
            acc1 = __builtin_amdgcn_mfma_f32_16x16x32_f16(hf[ks], w1.f, acc1, 0, 0, 0);
            acc2 = __builtin_amdgcn_mfma_f32_16x16x32_f16(hf[ks], w2.f, acc2, 0, 0, 0);
            acc3 = __builtin_amdgcn_mfma_f32_16x16x32_f16(hf[ks], w3.f, acc3, 0, 0, 0);
        }
        if (lane < 16) {
            gates[(wv * 4 + 0) * 16 + lane] = acc0[0];
            gates[(wv * 4 + 1) * 16 + lane] = acc1[0];
            gates[(wv * 4 + 2) * 16 + lane] = acc2[0];
            gates[(wv * 4 + 3) * 16 + lane] = acc3[0];
        }
        __syncthreads();
        if (tid < HH) {
            float gi = gates[tid] + pc0;
            float gf = gates[HH + tid] + pc1;
            float gg = gates[2 * HH + tid] + pc2;
            float go = gates[3 * HH + tid] + pc3;
            float si = 1.f / (1.f + __expf(-gi));
            float sf = 1.f / (1.f + __expf(-gf));
            float so = 1.f / (1.f + __expf(-go));
            float tg = 1.f - 2.f / (__expf(2.f * gg) + 1.f);
            c = sf * c + si * tg;
            float hn = so * (1.f - 2.f / (__expf(2.f * c) + 1.f));
            __half hh = __float2half(hn);
            hs[tid] = __half_as_ushort(hh);
            hlast = __half2float(hh);
            houtb[(size_t)t * HH + tid] = hh;
        }
        __syncthreads();
        pc0 = pn0; pc1 = pn1; pc2 = pn2; pc3 = pn3;
    }
    if (tid < HH) { hstb[tid] = hlast; cstb[tid] = c; }
}

// ---------------- epilogue ----------------
__global__ void gather_last(const __half* __restrict__ hfin, const int* __restrict__ lens,
                            float* __restrict__ last) {
    int idx = blockIdx.x * blockDim.x + threadIdx.x;
    if (idx >= BB * HH) return;
    int b = idx / HH, d = idx % HH;
    int t = lens[b] - 1;
    t = t < 0 ? 0 : (t > SS - 1 ? SS - 1 : t);
    last[idx] = __half2float(hfin[((size_t)b * SS + t) * HH + d]);
}

__global__ __launch_bounds__(256) void post_gemm(const float* __restrict__ A,
                                                 const float* __restrict__ Bw,
                                                 const float* __restrict__ pb,
                                                 float* __restrict__ Cb) {
    __shared__ float As[16][68];
    __shared__ float Bs[16][68];
    int n0 = blockIdx.x * 64;
    int tid = threadIdx.x;
    int kk = tid & 15, q = tid >> 4;
    int tx = tid & 15, ty = tid >> 4;
    float acc[4][4];
    #pragma unroll
    for (int i = 0; i < 4; ++i)
        #pragma unroll
        for (int jj = 0; jj < 4; ++jj) acc[i][jj] = 0.f;
    for (int kt = 0; kt < 12; ++kt) {
        int kidx = kt * 16 + kk;
        bool kval = kidx < HH;
        #pragma unroll
        for (int r = 0; r < 4; ++r)
            As[kk][q + (r << 4)] = kval ? A[(size_t)(q + (r << 4)) * HH + kidx] : 0.f;
        #pragma unroll
        for (int r = 0; r < 4; ++r)
            Bs[kk][q + (r << 4)] = kval ? Bw[(size_t)(n0 + q + (r << 4)) * HH + kidx] : 0.f;
        __syncthreads();
        #pragma unroll
        for (int k = 0; k < 16; ++k) {
            float a[4], bv[4];
            #pragma unroll
            for (int i = 0; i < 4; ++i) a[i] = As[k][ty + (i << 4)];
            #pragma unroll
            for (int jj = 0; jj < 4; ++jj) bv[jj] = Bs[k][(tx << 2) + jj];
            #pragma unroll
            for (int i = 0; i < 4; ++i)
                #pragma unroll
                for (int jj = 0; jj < 4; ++jj) acc[i][jj] = fmaf(a[i], bv[jj], acc[i][jj]);
        }
        __syncthreads();
    }
    #pragma unroll
    for (int i = 0; i < 4; ++i) {
        int m = ty + (i << 4);
        #pragma unroll
        for (int jj = 0; jj < 4; ++jj) {
            int g = n0 + (tx << 2) + jj;
            float v = acc[i][jj] + pb[g];
            Cb[(size_t)m * NPOST + g] = v > 0.f ? v : 0.01f * v;
        }
    }
}

__global__ __launch_bounds__(256) void up_gemm(const float* __restrict__ A,
                                               const float* __restrict__ Bw,
                                               float* __restrict__ part) {
    __shared__ float As[16][68];
    __shared__ float Bs[16][68];
    int n0 = blockIdx.x * 64;
    int k0 = blockIdx.y * (NPOST / KSPL);
    float* Pb = part + (size_t)blockIdx.y * BB * NOUTP;
    int tid = threadIdx.x;
    int kk = tid & 15, q = tid >> 4;
    int tx = tid & 15, ty = tid >> 4;
    float acc[4][4];
    #pragma unroll
    for (int i = 0; i < 4; ++i)
        #pragma unroll
        for (int jj = 0; jj < 4; ++jj) acc[i][jj] = 0.f;
    for (int kt = 0; kt < (NPOST / KSPL) / 16; ++kt) {
        int kidx = k0 + kt * 16 + kk;
        #pragma unroll
        for (int r = 0; r < 4; ++r)
            As[kk][q + (r << 4)] = A[(size_t)(q + (r << 4)) * NPOST + kidx];
        #pragma unroll
        for (int r = 0; r < 4; ++r) {
            int g = n0 + q + (r << 4);
            Bs[kk][q + (r << 4)] = (g < NOUT) ? Bw[(size_t)g * NPOST + kidx] : 0.f;
        }
        __syncthreads();
        #pragma unroll
        for (int k = 0; k < 16; ++k) {
            float a[4], bv[4];
            #pragma unroll
            for (int i = 0; i < 4; ++i) a[i] = As[k][ty + (i << 4)];
            #pragma unroll
            for (int jj = 0; jj < 4; ++jj) bv[jj] = Bs[k][(tx << 2) + jj];
            #pragma unroll
            for (int i = 0; i < 4; ++i)
                #pragma unroll
                for (int jj = 0; jj < 4; ++jj) acc[i][jj] = fmaf(a[i], bv[jj], acc[i][jj]);
        }
        __syncthreads();
    }
    #pragma unroll
    for (int i = 0; i < 4; ++i) {
        int m = ty + (i << 4);
        #pragma unroll
        for (int jj = 0; jj < 4; ++jj) {
            int g = n0 + (tx << 2) + jj;
            Pb[(size_t)m * NOUTP + g] = acc[i][jj];
        }
    }
}

__global__ void up_reduce(const float* __restrict__ part, const float* __restrict__ ub,
                          float* __restrict__ out) {
    int idx = blockIdx.x * blockDim.x + threadIdx.x;
    if (idx >= BB * NOUT) return;
    int b = idx / NOUT, o = idx % NOUT;
    float acc = ub[o];
    #pragma unroll
    for (int ks = 0; ks < KSPL; ++ks)
        acc += part[((size_t)ks * BB + b) * NOUTP + o];
    out[(size_t)b * NOUT + o] = acc;
}

extern "C" void kernel_launch(void* const* d_in, const int* in_sizes, int n_in,
                              void* d_out, int out_size, void* d_ws, size_t ws_size,
                              hipStream_t stream) {
    const float* x        = (const float*)d_in[0];
    const int*   lens     = (const int*)d_in[1];
    const float* conv_w   = (const float*)d_in[2];
    const float* conv_b   = (const float*)d_in[3];
    const float* wih0     = (const float*)d_in[4];
    const float* wih_rest = (const float*)d_in[5];
    const float* whh      = (const float*)d_in[6];
    const float* bih      = (const float*)d_in[7];
    const float* bhh      = (const float*)d_in[8];
    const float* post_w   = (const float*)d_in[9];
    const float* post_b   = (const float*)d_in[10];
    const float* up_w     = (const float*)d_in[11];
    const float* up_b     = (const float*)d_in[12];
    float* out = (float*)d_out;
    (void)in_sizes; (void)n_in; (void)out_size;

    auto pad = [](size_t v) { return (v + 255) & ~(size_t)255; };
    const size_t szMel   = (size_t)BB * SS * MEL * 2;
    const size_t szH     = (size_t)BB * SS * HH * 2;
    const size_t szPre0  = (size_t)BB * SS * G4 * 2;
    const size_t szSlot  = (size_t)BB * CH * G4 * 2;
    const size_t szWmf   = (size_t)NL * NCG * NKS * 64 * 16;   // 1.18 MB
    const size_t szWih   = (size_t)NL * G4 * KPAIR * 4;
    const size_t szBsum  = (size_t)NL * G4 * 4;
    const size_t szState = (size_t)NL * BB * HH * 4;
    const size_t szLast  = (size_t)BB * HH * 4;
    const size_t szPost  = (size_t)BB * NPOST * 4;
    const size_t szPart  = (size_t)KSPL * BB * NOUTP * 4;

    size_t commonSmall = pad(szWmf) + pad(szWih) + pad(szBsum) + 2 * pad(szState) +
                         pad(szLast) + pad(szPost) + pad(szPart) + 4096;
    size_t need1 = pad(szMel) + 4 * pad(szH) + pad(szPre0) + 3 * pad(szSlot) + commonSmall;
    size_t need2 = pad(szMel) + 4 * pad(szH) + 4 * pad(szSlot) + commonSmall;
    int tier = (ws_size >= need1) ? 1 : ((ws_size >= need2) ? 2 : 3);

    char* wsp = (char*)d_ws;
    size_t off = 0;
    auto alloc = [&](size_t bytes) -> void* {
        void* p = wsp + off;
        off = (off + bytes + 255) & ~(size_t)255;
        return p;
    };

    __half* melF = (__half*)alloc(szMel);
    __half* hbuf[NL];
    if (tier <= 2) {
        for (int l = 0; l < NL; ++l) hbuf[l] = (__half*)alloc(szH);
    } else {
        __half* p0 = (__half*)alloc(szH);
        __half* p1 = (__half*)alloc(szH);
        hbuf[0] = p0; hbuf[1] = p1; hbuf[2] = p0; hbuf[3] = p1;
    }
    __half* pre0 = nullptr;
    __half* slot[NL] = {nullptr, nullptr, nullptr, nullptr};
    if (tier == 1) {
        pre0 = (__half*)alloc(szPre0);
        for (int l = 1; l < NL; ++l) slot[l] = (__half*)alloc(szSlot);
    } else if (tier == 2) {
        for (int l = 0; l < NL; ++l) slot[l] = (__half*)alloc(szSlot);
    } else {
        slot[0] = (__half*)alloc(szSlot);
        for (int l = 1; l < NL; ++l) slot[l] = slot[0];
    }
    uint4* wmf = (uint4*)alloc(szWmf);
    unsigned int* wih16 = (unsigned int*)alloc(szWih);
    float* bsum  = (float*)alloc(szBsum);
    float* hstates = (float*)alloc(szState);
    float* cstates = (float*)alloc(szState);
    float* lastb = (float*)alloc(szLast);
    float* postb = (float*)alloc(szPost);
    float* partb = (float*)alloc(szPart);

    prep_wmf<<<(NL * NCG * NKS * 64 + 255) / 256, 256, 0, stream>>>(whh, wmf);
    prep_wih16<<<(NL * G4 * KPAIR + 255) / 256, 256, 0, stream>>>(wih0, wih_rest, wih16);
    prep_bsum<<<(NL * G4 + 255) / 256, 256, 0, stream>>>(bih, bhh, bsum);

    {
        __half* m0 = hbuf[0];
        __half* m1 = (__half*)((char*)hbuf[0] + pad(szMel));
        mel_block<float><<<dim3(BB, SS / TT), 256, 0, stream>>>(x, m0, conv_w + 0 * 900, conv_b + 0 * 60);
        mel_block<__half><<<dim3(BB, SS / TT), 256, 0, stream>>>(m0, m1, conv_w + 1 * 900, conv_b + 1 * 60);
        mel_block<__half><<<dim3(BB, SS / TT), 256, 0, stream>>>(m1, melF, conv_w + 2 * 900, conv_b + 2 * 60);
    }

    auto setGemmJob = [&](GemmArgs& ga, int nj, int l, int c) {
        ga.A[nj]  = (l == 0) ? melF : hbuf[l - 1];
        ga.K[nj]  = (l == 0) ? MEL : HH;
        ga.KT[nj] = (l == 0) ? 4 : 12;
        ga.W[nj]  = wih16 + (size_t)l * G4 * KPAIR;
        ga.bs[nj] = bsum + l * G4;
        if (tier == 1 && l == 0) {
            ga.C[nj] = pre0 + (size_t)c * CH * G4;
            ga.cbs[nj] = (size_t)SS * G4;
        } else {
            ga.C[nj] = slot[l];
            ga.cbs[nj] = (size_t)CH * G4;
        }
        ga.t0[nj] = c * CH;
    };
    auto setScanJob = [&](ScanArgs& sa, int nj, int l, int c) {
        if (tier == 1 && l == 0) {
            sa.pre[nj] = pre0 + (size_t)c * CH * G4;
            sa.pbs[nj] = (size_t)SS * G4;
        } else {
            sa.pre[nj] = slot[l];
            sa.pbs[nj] = (size_t)CH * G4;
        }
        sa.wmf[nj]  = wmf + (size_t)l * NCG * NKS * 64;
        sa.hout[nj] = hbuf[l];
        sa.hst[nj]  = hstates + (size_t)l * BB * HH;
        sa.cst[nj]  = cstates + (size_t)l * BB * HH;
        sa.t0[nj]   = c * CH;
    };

    if (tier <= 2) {
        if (tier == 1) {
            GemmArgs ga{};
            for (int c = 0; c < NCH; ++c) setGemmJob(ga, c, 0, c);
            gemm_pre<<<dim3(BB, 12, NCH), 256, 0, stream>>>(ga);
        }
        int lmin = (tier == 1) ? 1 : 0;
        for (int w = 0; w < NCH + NL - 1; ++w) {
            GemmArgs ga{};
            int njg = 0;
            for (int l = lmin; l < NL; ++l) {
                int c = w - l;
                if (c < 0 || c >= NCH) continue;
                setGemmJob(ga, njg++, l, c);
            }
            if (njg) gemm_pre<<<dim3(BB, 12, njg), 256, 0, stream>>>(ga);
            ScanArgs sa{};
            int njs = 0;
            for (int l = 0; l < NL; ++l) {
                int c = w - l;
                if (c < 0 || c >= NCH) continue;
                setScanJob(sa, njs++, l, c);
            }
            if (njs) lstm_scan<<<dim3(njs * BB), 768, 0, stream>>>(sa);
        }
    } else {
        for (int l = 0; l < NL; ++l) {
            for (int c = 0; c < NCH; ++c) {
                GemmArgs ga{}; ScanArgs sa{};
                setGemmJob(ga, 0, l, c);
                gemm_pre<<<dim3(BB, 12, 1), 256, 0, stream>>>(ga);
                setScanJob(sa, 0, l, c);
                lstm_scan<<<dim3(BB), 768, 0, stream>>>(sa);
            }
        }
    }

    gather_last<<<(BB * HH + 255) / 256, 256, 0, stream>>>(hbuf[NL - 1], lens, lastb);
    post_gemm<<<NPOST / 64, 256, 0, stream>>>(lastb, post_w, post_b, postb);
    up_gemm<<<dim3(NOUTP / 64, KSPL), 256, 0, stream>>>(postb, up_w, partb);
    up_reduce<<<(BB * NOUT + 255) / 256, 256, 0, stream>>>(partb, up_b, out);
}